// Round 3
// baseline (684.309 us; speedup 1.0000x reference)
//
#include <hip/hip_runtime.h>
#include <cstdint>
#include <cstddef>

// ---------------------------------------------------------------------------
// DecoderBlock (cross-attn + MLP), MI355X gfx950.
// fp32 in/out, bf16 MFMA compute.
// B=4, Nq=1024, Nk=2048, DIM=1024, H=16, HD=64, HID=4096.
// ---------------------------------------------------------------------------

typedef __attribute__((ext_vector_type(8))) short bf16x8;
typedef __attribute__((ext_vector_type(4))) float f32x4;

__device__ __forceinline__ short f2b(float f) {
    unsigned u = __builtin_bit_cast(unsigned, f);
    unsigned r = (u + 0x7FFFu + ((u >> 16) & 1u)) >> 16;   // RNE
    return (short)r;
}

__device__ __forceinline__ f32x4 mfma16(bf16x8 a, bf16x8 b, f32x4 c) {
    return __builtin_amdgcn_mfma_f32_16x16x32_bf16(a, b, c, 0, 0, 0);
}

__device__ __forceinline__ void gload16(const void* g, void* l) {
    __builtin_amdgcn_global_load_lds(
        (const __attribute__((address_space(1))) unsigned int*)g,
        (__attribute__((address_space(3))) unsigned int*)l, 16, 0, 0);
}

// ------------------------------- prep kernels ------------------------------

// fp32 [R][C] -> bf16 [C][R]
__global__ __launch_bounds__(256) void transpose_f2b(
    const float* __restrict__ in, short* __restrict__ out, int R, int C) {
    __shared__ float tile[32][33];
    const int c0 = blockIdx.x * 32, r0 = blockIdx.y * 32;
    const int tx = threadIdx.x, ty = threadIdx.y;   // (32,8)
#pragma unroll
    for (int i = 0; i < 4; ++i)
        tile[ty + 8 * i][tx] = in[(size_t)(r0 + ty + 8 * i) * C + c0 + tx];
    __syncthreads();
#pragma unroll
    for (int i = 0; i < 4; ++i)
        out[(size_t)(c0 + ty + 8 * i) * R + r0 + tx] = f2b(tile[tx][ty + 8 * i]);
}

// fp32 -> bf16 flat (n4 = count/4)
__global__ __launch_bounds__(256) void conv_f2b(
    const float* __restrict__ in, short* __restrict__ out, int n4) {
    int i = blockIdx.x * 256 + threadIdx.x;
    if (i < n4) {
        float4 v = reinterpret_cast<const float4*>(in)[i];
        short4 o;
        o.x = f2b(v.x); o.y = f2b(v.y); o.z = f2b(v.z); o.w = f2b(v.w);
        reinterpret_cast<short4*>(out)[i] = o;
    }
}

// LayerNorm over D=1024, fp32 in -> bf16 out. One row per block (256 thr).
__global__ __launch_bounds__(256) void ln_bf16(
    const float* __restrict__ x, const float* __restrict__ g,
    const float* __restrict__ bb, short* __restrict__ out) {
    const int row = blockIdx.x, tid = threadIdx.x;
    float4 v = reinterpret_cast<const float4*>(x + (size_t)row * 1024)[tid];
    float s = v.x + v.y + v.z + v.w;
    float q = v.x * v.x + v.y * v.y + v.z * v.z + v.w * v.w;
#pragma unroll
    for (int off = 32; off; off >>= 1) {
        s += __shfl_down(s, off);
        q += __shfl_down(q, off);
    }
    __shared__ float ss[4], sq[4];
    const int wave = tid >> 6, lane = tid & 63;
    if (lane == 0) { ss[wave] = s; sq[wave] = q; }
    __syncthreads();
    s = ss[0] + ss[1] + ss[2] + ss[3];
    q = sq[0] + sq[1] + sq[2] + sq[3];
    const float mu = s * (1.f / 1024.f);
    const float var = q * (1.f / 1024.f) - mu * mu;
    const float rs = rsqrtf(var + 1e-5f);
    float4 gg = reinterpret_cast<const float4*>(g)[tid];
    float4 bv = reinterpret_cast<const float4*>(bb)[tid];
    short4 o;
    o.x = f2b((v.x - mu) * rs * gg.x + bv.x);
    o.y = f2b((v.y - mu) * rs * gg.y + bv.y);
    o.z = f2b((v.z - mu) * rs * gg.z + bv.z);
    o.w = f2b((v.w - mu) * rs * gg.w + bv.w);
    reinterpret_cast<short4*>(out + (size_t)row * 1024)[tid] = o;
}

// vbuf bf16 [B][2048][H*64] -> VT bf16 [B][H][64][2048]
__global__ __launch_bounds__(256) void transpose_v(
    const short* __restrict__ vbuf, short* __restrict__ VT) {
    __shared__ short t[32][33];
    const int b = blockIdx.z >> 4, h = blockIdx.z & 15;
    const int n0 = blockIdx.x * 32, d0 = blockIdx.y * 32;
    const int tx = threadIdx.x, ty = threadIdx.y;   // (32,8)
#pragma unroll
    for (int i = 0; i < 4; ++i)
        t[ty + 8 * i][tx] =
            vbuf[(size_t)(b * 2048 + n0 + ty + 8 * i) * 1024 + h * 64 + d0 + tx];
    __syncthreads();
#pragma unroll
    for (int i = 0; i < 4; ++i)
        VT[(size_t)((b * 16 + h) * 64 + d0 + ty + 8 * i) * 2048 + n0 + tx] =
            t[tx][ty + 8 * i];
}

// ------------------------------- GEMM --------------------------------------
// C[M,N] = act( (A[M,K] @ BT[N,K]^T + bias) * scale ) + resid
// A,BT bf16 row-major-along-K. 128x128 tile, 4 waves, BK=32.
template <int BIAS, int RESID, int GELU, int OUTF>
__global__ __launch_bounds__(256) void gemm_bt(
    const short* __restrict__ A, const short* __restrict__ BT,
    const float* __restrict__ bias, const float* __restrict__ resid,
    void* __restrict__ out, int M, int N, int K, float scale) {
    __shared__ __align__(16) short As[128 * 32];
    __shared__ __align__(16) short Bs[128 * 32];
    const int tid = threadIdx.x;
    const int wave = tid >> 6, lane = tid & 63;
    const int l15 = lane & 15, lhi = lane >> 4;
    const int bm = blockIdx.x, bn = blockIdx.y;
    const int wm = (wave >> 1) * 64, wn = (wave & 1) * 64;

    f32x4 acc[4][4];
#pragma unroll
    for (int i = 0; i < 4; ++i)
#pragma unroll
        for (int j = 0; j < 4; ++j) acc[i][j] = (f32x4){0.f, 0.f, 0.f, 0.f};

    for (int k0 = 0; k0 < K; k0 += 32) {
#pragma unroll
        for (int c = 0; c < 2; ++c) {
            const int ob = wave * 2048 + c * 1024;       // wave-uniform LDS base
            const int o = ob + lane * 16;                // per-lane byte in tile
            const int row = o >> 6, kb = o & 63;         // 64B per 32-elem row
            const char* ga = (const char*)A + ((size_t)(bm * 128 + row) * K + k0) * 2 + kb;
            const char* gb = (const char*)BT + ((size_t)(bn * 128 + row) * K + k0) * 2 + kb;
            gload16(ga, (char*)As + ob);
            gload16(gb, (char*)Bs + ob);
        }
        __syncthreads();
        bf16x8 af[4], bfr[4];
#pragma unroll
        for (int t = 0; t < 4; ++t) {
            af[t]  = *(const bf16x8*)&As[(wm + t * 16 + l15) * 32 + lhi * 8];
            bfr[t] = *(const bf16x8*)&Bs[(wn + t * 16 + l15) * 32 + lhi * 8];
        }
#pragma unroll
        for (int mt = 0; mt < 4; ++mt)
#pragma unroll
            for (int nt = 0; nt < 4; ++nt)
                acc[mt][nt] = mfma16(af[mt], bfr[nt], acc[mt][nt]);
        __syncthreads();
    }

#pragma unroll
    for (int mt = 0; mt < 4; ++mt)
#pragma unroll
        for (int nt = 0; nt < 4; ++nt)
#pragma unroll
            for (int r = 0; r < 4; ++r) {
                const int row = bm * 128 + wm + mt * 16 + lhi * 4 + r;
                const int col = bn * 128 + wn + nt * 16 + l15;
                float v = acc[mt][nt][r];
                if (BIAS) v += bias[col];
                v *= scale;
                if (GELU) v = 0.5f * v * (1.f + erff(v * 0.70710678118f));
                if (RESID) v += resid[(size_t)row * N + col];
                if (OUTF)
                    ((float*)out)[(size_t)row * N + col] = v;
                else
                    ((short*)out)[(size_t)row * N + col] = f2b(v);
            }
}

// ---------------------------- flash attention ------------------------------
// Q: bf16 [B*1024][1024] (already scaled by 1/8), K: bf16 [B*2048][1024],
// VT: bf16 [B][H][64][2048], ctx out: bf16 [B*1024][1024].
// grid (Nq/64, B*H), 4 waves; each wave owns 16 q-rows.
__global__ __launch_bounds__(256) void attn_flash(
    const short* __restrict__ Q, const short* __restrict__ Kb,
    const short* __restrict__ VT, short* __restrict__ ctx) {
    __shared__ __align__(16) short p_lds[4 * 640];   // per-wave 16 rows x 40 (32 used)
    const int tid = threadIdx.x, wave = tid >> 6, lane = tid & 63;
    const int l15 = lane & 15, lhi = lane >> 4;
    const int b = blockIdx.y >> 4, h = blockIdx.y & 15;
    const int q0row = blockIdx.x * 64 + wave * 16;

    const short* qp = Q + ((size_t)(b * 1024 + q0row + l15) * 1024 + h * 64);
    const bf16x8 qf0 = *(const bf16x8*)(qp + lhi * 8);
    const bf16x8 qf1 = *(const bf16x8*)(qp + 32 + lhi * 8);

    f32x4 oa[4];
#pragma unroll
    for (int i = 0; i < 4; ++i) oa[i] = (f32x4){0.f, 0.f, 0.f, 0.f};
    float m[4] = {-1e30f, -1e30f, -1e30f, -1e30f};
    float l[4] = {0.f, 0.f, 0.f, 0.f};

    const short* kbase = Kb + ((size_t)(b * 2048) * 1024 + h * 64);
    const short* vbase = VT + (size_t)(b * 16 + h) * 64 * 2048;
    short* plw = p_lds + wave * 640;

    for (int kt = 0; kt < 2048; kt += 32) {
        f32x4 s0 = (f32x4){0.f, 0.f, 0.f, 0.f};
        f32x4 s1 = (f32x4){0.f, 0.f, 0.f, 0.f};
        const short* k0p = kbase + (size_t)(kt + l15) * 1024;
        const short* k1p = kbase + (size_t)(kt + 16 + l15) * 1024;
        s0 = mfma16(qf0, *(const bf16x8*)(k0p + lhi * 8), s0);
        s0 = mfma16(qf1, *(const bf16x8*)(k0p + 32 + lhi * 8), s0);
        s1 = mfma16(qf0, *(const bf16x8*)(k1p + lhi * 8), s1);
        s1 = mfma16(qf1, *(const bf16x8*)(k1p + 32 + lhi * 8), s1);

#pragma unroll
        for (int r = 0; r < 4; ++r) {
            float cm = fmaxf(s0[r], s1[r]);
#pragma unroll
            for (int off = 1; off < 16; off <<= 1)
                cm = fmaxf(cm, __shfl_xor(cm, off, 16));
            const float nm = fmaxf(m[r], cm);
            const float sc = __expf(m[r] - nm);
            const float p0 = __expf(s0[r] - nm);
            const float p1 = __expf(s1[r] - nm);
            float rs = p0 + p1;
#pragma unroll
            for (int off = 1; off < 16; off <<= 1)
                rs += __shfl_xor(rs, off, 16);
            l[r] = l[r] * sc + rs;
            m[r] = nm;
            oa[0][r] *= sc; oa[1][r] *= sc; oa[2][r] *= sc; oa[3][r] *= sc;
            const int rp = lhi * 4 + r;
            plw[rp * 40 + l15] = f2b(p0);
            plw[rp * 40 + 16 + l15] = f2b(p1);
        }
        const bf16x8 pa = *(const bf16x8*)(plw + l15 * 40 + lhi * 8);
#pragma unroll
        for (int ct = 0; ct < 4; ++ct) {
            const bf16x8 vb =
                *(const bf16x8*)(vbase + (size_t)(ct * 16 + l15) * 2048 + kt + lhi * 8);
            oa[ct] = mfma16(pa, vb, oa[ct]);
        }
    }

#pragma unroll
    for (int r = 0; r < 4; ++r) {
        const float inv = 1.f / l[r];
        const int qrow = q0row + lhi * 4 + r;
        short* cp = ctx + ((size_t)(b * 1024 + qrow) * 1024 + h * 64);
#pragma unroll
        for (int ct = 0; ct < 4; ++ct) cp[ct * 16 + l15] = f2b(oa[ct][r] * inv);
    }
}

// ------------------------------- launcher ----------------------------------

extern "C" void kernel_launch(void* const* d_in, const int* in_sizes, int n_in,
                              void* d_out, int out_size, void* d_ws, size_t ws_size,
                              hipStream_t stream) {
    const float* tgt  = (const float*)d_in[0];
    const float* emb  = (const float*)d_in[1];
    const float* ln_g = (const float*)d_in[2];
    const float* ln_b = (const float*)d_in[3];
    const float* wq = (const float*)d_in[4];  const float* bq = (const float*)d_in[5];
    const float* wk = (const float*)d_in[6];  const float* bk = (const float*)d_in[7];
    const float* wv = (const float*)d_in[8];  const float* bv = (const float*)d_in[9];
    const float* wo = (const float*)d_in[10]; const float* bo = (const float*)d_in[11];
    const float* w1 = (const float*)d_in[12]; const float* b1 = (const float*)d_in[13];
    const float* w2 = (const float*)d_in[14]; const float* b2 = (const float*)d_in[15];

    char* ws = (char*)d_ws;
    const size_t MB = 1024 * 1024;
    short* wqT  = (short*)(ws + 0 * MB);
    short* wkT  = (short*)(ws + 2 * MB);
    short* wvT  = (short*)(ws + 4 * MB);
    short* woT  = (short*)(ws + 6 * MB);
    short* w1T  = (short*)(ws + 8 * MB);    // 8MB
    short* w2T  = (short*)(ws + 16 * MB);   // 8MB
    float* tgt2 = (float*)(ws + 24 * MB);   // 16MB (lifetime disjoint from embB)
    short* embB = (short*)(ws + 40 * MB);   // 16MB (dead after K/V GEMMs)
    short* qn   = (short*)(ws + 56 * MB);   // 8MB (reused as hn)
    short* qbuf = (short*)(ws + 64 * MB);   // 8MB
    short* kbuf = (short*)(ws + 72 * MB);   // 16MB
    short* vbuf = (short*)(ws + 88 * MB);   // 16MB
    short* VT   = (short*)(ws + 104 * MB);  // 16MB
    short* ctx  = (short*)(ws + 120 * MB);  // 8MB
    short* h1   = (short*)(ws + 64 * MB);   // 32MB, reuses q/k/v region (dead by MLP)
    float* outp = (float*)d_out;

    const dim3 tb(32, 8);
    // weights -> bf16 transposed
    transpose_f2b<<<dim3(32, 32), tb, 0, stream>>>(wq, wqT, 1024, 1024);
    transpose_f2b<<<dim3(32, 32), tb, 0, stream>>>(wk, wkT, 1024, 1024);
    transpose_f2b<<<dim3(32, 32), tb, 0, stream>>>(wv, wvT, 1024, 1024);
    transpose_f2b<<<dim3(32, 32), tb, 0, stream>>>(wo, woT, 1024, 1024);
    transpose_f2b<<<dim3(128, 32), tb, 0, stream>>>(w1, w1T, 1024, 4096);
    transpose_f2b<<<dim3(32, 128), tb, 0, stream>>>(w2, w2T, 4096, 1024);
    // emb -> bf16
    conv_f2b<<<8192, 256, 0, stream>>>(emb, embB, 8192 * 1024 / 4);
    // qn = LN(tgt)
    ln_bf16<<<4096, 256, 0, stream>>>(tgt, ln_g, ln_b, qn);
    // q = (qn@wq + bq)/8 ; k/v = emb@w + b
    gemm_bt<1, 0, 0, 0><<<dim3(32, 8), 256, 0, stream>>>(qn, wqT, bq, nullptr, qbuf, 4096, 1024, 1024, 0.125f);
    gemm_bt<1, 0, 0, 0><<<dim3(64, 8), 256, 0, stream>>>(embB, wkT, bk, nullptr, kbuf, 8192, 1024, 1024, 1.f);
    gemm_bt<1, 0, 0, 0><<<dim3(64, 8), 256, 0, stream>>>(embB, wvT, bv, nullptr, vbuf, 8192, 1024, 1024, 1.f);
    transpose_v<<<dim3(64, 2, 64), tb, 0, stream>>>(vbuf, VT);
    // attention
    attn_flash<<<dim3(16, 64), 256, 0, stream>>>(qbuf, kbuf, VT, ctx);
    // tgt2 = tgt + ctx@wo + bo
    gemm_bt<1, 1, 0, 1><<<dim3(32, 8), 256, 0, stream>>>(ctx, woT, bo, tgt, tgt2, 4096, 1024, 1024, 1.f);
    // hn = LN(tgt2)
    ln_bf16<<<4096, 256, 0, stream>>>(tgt2, ln_g, ln_b, qn);
    // h1 = gelu(hn@w1 + b1)
    gemm_bt<1, 0, 1, 0><<<dim3(32, 32), 256, 0, stream>>>(qn, w1T, b1, nullptr, h1, 4096, 4096, 1024, 1.f);
    // out = tgt2 + h1@w2 + b2
    gemm_bt<1, 1, 0, 1><<<dim3(32, 8), 256, 0, stream>>>(h1, w2T, b2, tgt2, outp, 4096, 1024, 4096, 1.f);

    (void)in_sizes; (void)n_in; (void)out_size; (void)ws_size;
}

// Round 5
// 563.364 us; speedup vs baseline: 1.2147x; 1.2147x over previous
//
#include <hip/hip_runtime.h>
#include <cstdint>
#include <cstddef>

// ---------------------------------------------------------------------------
// DecoderBlock (cross-attn + MLP), MI355X gfx950.
// fp32 in/out, bf16 MFMA compute.
// B=4, Nq=1024, Nk=2048, DIM=1024, H=16, HD=64, HID=4096.
// ---------------------------------------------------------------------------

typedef __attribute__((ext_vector_type(8))) short bf16x8;
typedef __attribute__((ext_vector_type(4))) float f32x4;

__device__ __forceinline__ short f2b(float f) {
    unsigned u = __builtin_bit_cast(unsigned, f);
    unsigned r = (u + 0x7FFFu + ((u >> 16) & 1u)) >> 16;   // RNE
    return (short)r;
}

__device__ __forceinline__ f32x4 mfma16(bf16x8 a, bf16x8 b, f32x4 c) {
    return __builtin_amdgcn_mfma_f32_16x16x32_bf16(a, b, c, 0, 0, 0);
}

__device__ __forceinline__ void gload16(const void* g, void* l) {
    __builtin_amdgcn_global_load_lds(
        (const __attribute__((address_space(1))) unsigned int*)g,
        (__attribute__((address_space(3))) unsigned int*)l, 16, 0, 0);
}

// ------------------------------- prep kernels ------------------------------

// fp32 [R][C] -> bf16 [C][R]
__global__ __launch_bounds__(256) void transpose_f2b(
    const float* __restrict__ in, short* __restrict__ out, int R, int C) {
    __shared__ float tile[32][33];
    const int c0 = blockIdx.x * 32, r0 = blockIdx.y * 32;
    const int tx = threadIdx.x, ty = threadIdx.y;   // (32,8)
#pragma unroll
    for (int i = 0; i < 4; ++i)
        tile[ty + 8 * i][tx] = in[(size_t)(r0 + ty + 8 * i) * C + c0 + tx];
    __syncthreads();
#pragma unroll
    for (int i = 0; i < 4; ++i)
        out[(size_t)(c0 + ty + 8 * i) * R + r0 + tx] = f2b(tile[tx][ty + 8 * i]);
}

// fp32 -> bf16 flat (n4 = count/4)
__global__ __launch_bounds__(256) void conv_f2b(
    const float* __restrict__ in, short* __restrict__ out, int n4) {
    int i = blockIdx.x * 256 + threadIdx.x;
    if (i < n4) {
        float4 v = reinterpret_cast<const float4*>(in)[i];
        short4 o;
        o.x = f2b(v.x); o.y = f2b(v.y); o.z = f2b(v.z); o.w = f2b(v.w);
        reinterpret_cast<short4*>(out)[i] = o;
    }
}

// LayerNorm over D=1024, fp32 in -> bf16 out. One row per block (256 thr).
__global__ __launch_bounds__(256) void ln_bf16(
    const float* __restrict__ x, const float* __restrict__ g,
    const float* __restrict__ bb, short* __restrict__ out) {
    const int row = blockIdx.x, tid = threadIdx.x;
    float4 v = reinterpret_cast<const float4*>(x + (size_t)row * 1024)[tid];
    float s = v.x + v.y + v.z + v.w;
    float q = v.x * v.x + v.y * v.y + v.z * v.z + v.w * v.w;
#pragma unroll
    for (int off = 32; off; off >>= 1) {
        s += __shfl_down(s, off);
        q += __shfl_down(q, off);
    }
    __shared__ float ss[4], sq[4];
    const int wave = tid >> 6, lane = tid & 63;
    if (lane == 0) { ss[wave] = s; sq[wave] = q; }
    __syncthreads();
    s = ss[0] + ss[1] + ss[2] + ss[3];
    q = sq[0] + sq[1] + sq[2] + sq[3];
    const float mu = s * (1.f / 1024.f);
    const float var = q * (1.f / 1024.f) - mu * mu;
    const float rs = rsqrtf(var + 1e-5f);
    float4 gg = reinterpret_cast<const float4*>(g)[tid];
    float4 bv = reinterpret_cast<const float4*>(bb)[tid];
    short4 o;
    o.x = f2b((v.x - mu) * rs * gg.x + bv.x);
    o.y = f2b((v.y - mu) * rs * gg.y + bv.y);
    o.z = f2b((v.z - mu) * rs * gg.z + bv.z);
    o.w = f2b((v.w - mu) * rs * gg.w + bv.w);
    reinterpret_cast<short4*>(out + (size_t)row * 1024)[tid] = o;
}

// vbuf bf16 [B][2048][H*64] -> VT bf16 [B][H][64][2048]
__global__ __launch_bounds__(256) void transpose_v(
    const short* __restrict__ vbuf, short* __restrict__ VT) {
    __shared__ short t[32][33];
    const int b = blockIdx.z >> 4, h = blockIdx.z & 15;
    const int n0 = blockIdx.x * 32, d0 = blockIdx.y * 32;
    const int tx = threadIdx.x, ty = threadIdx.y;   // (32,8)
#pragma unroll
    for (int i = 0; i < 4; ++i)
        t[ty + 8 * i][tx] =
            vbuf[(size_t)(b * 2048 + n0 + ty + 8 * i) * 1024 + h * 64 + d0 + tx];
    __syncthreads();
#pragma unroll
    for (int i = 0; i < 4; ++i)
        VT[(size_t)((b * 16 + h) * 64 + d0 + ty + 8 * i) * 2048 + n0 + tx] =
            t[tx][ty + 8 * i];
}

// ------------------------------- GEMM --------------------------------------
// C[M,N] = act( (A[M,K] @ BT[N,K]^T + bias) * scale ) + resid
// A,BT bf16 row-major-along-K. 128x128 tile, 4 waves, BK=32.
template <int BIAS, int RESID, int GELU, int OUTF>
__global__ __launch_bounds__(256) void gemm_bt(
    const short* __restrict__ A, const short* __restrict__ BT,
    const float* __restrict__ bias, const float* __restrict__ resid,
    void* __restrict__ out, int M, int N, int K, float scale) {
    __shared__ __align__(16) short As[128 * 32];
    __shared__ __align__(16) short Bs[128 * 32];
    const int tid = threadIdx.x;
    const int wave = tid >> 6, lane = tid & 63;
    const int l15 = lane & 15, lhi = lane >> 4;
    const int bm = blockIdx.x, bn = blockIdx.y;
    const int wm = (wave >> 1) * 64, wn = (wave & 1) * 64;

    f32x4 acc[4][4];
#pragma unroll
    for (int i = 0; i < 4; ++i)
#pragma unroll
        for (int j = 0; j < 4; ++j) acc[i][j] = (f32x4){0.f, 0.f, 0.f, 0.f};

    for (int k0 = 0; k0 < K; k0 += 32) {
#pragma unroll
        for (int c = 0; c < 2; ++c) {
            const int ob = wave * 2048 + c * 1024;       // wave-uniform LDS base
            const int o = ob + lane * 16;                // per-lane byte in tile
            const int row = o >> 6, kb = o & 63;         // 64B per 32-elem row
            const char* ga = (const char*)A + ((size_t)(bm * 128 + row) * K + k0) * 2 + kb;
            const char* gb = (const char*)BT + ((size_t)(bn * 128 + row) * K + k0) * 2 + kb;
            gload16(ga, (char*)As + ob);
            gload16(gb, (char*)Bs + ob);
        }
        __syncthreads();
        bf16x8 af[4], bfr[4];
#pragma unroll
        for (int t = 0; t < 4; ++t) {
            af[t]  = *(const bf16x8*)&As[(wm + t * 16 + l15) * 32 + lhi * 8];
            bfr[t] = *(const bf16x8*)&Bs[(wn + t * 16 + l15) * 32 + lhi * 8];
        }
#pragma unroll
        for (int mt = 0; mt < 4; ++mt)
#pragma unroll
            for (int nt = 0; nt < 4; ++nt)
                acc[mt][nt] = mfma16(af[mt], bfr[nt], acc[mt][nt]);
        __syncthreads();
    }

#pragma unroll
    for (int mt = 0; mt < 4; ++mt)
#pragma unroll
        for (int nt = 0; nt < 4; ++nt)
#pragma unroll
            for (int r = 0; r < 4; ++r) {
                const int row = bm * 128 + wm + mt * 16 + lhi * 4 + r;
                const int col = bn * 128 + wn + nt * 16 + l15;
                float v = acc[mt][nt][r];
                if (BIAS) v += bias[col];
                v *= scale;
                if (GELU) v = 0.5f * v * (1.f + erff(v * 0.70710678118f));
                if (RESID) v += resid[(size_t)row * N + col];
                if (OUTF)
                    ((float*)out)[(size_t)row * N + col] = v;
                else
                    ((short*)out)[(size_t)row * N + col] = f2b(v);
            }
}

// ---------------------------- flash attention ------------------------------
// Q: bf16 [B*1024][1024] (pre-scaled by 1/8), K: bf16 [B*2048][1024],
// VT: bf16 [B][H][64][2048], ctx out: bf16 [B*1024][1024].
// grid (Nq/128, B*H), 4 waves; wave owns 32 q-rows (2 fragments).
// K/V staged in LDS, double-buffered, KVBLK=64, XOR-swizzled rows.
__global__ __launch_bounds__(256) void attn_flash(
    const short* __restrict__ Q, const short* __restrict__ Kb,
    const short* __restrict__ VT, short* __restrict__ ctx) {
    __shared__ __align__(16) short kls[2 * 4096];     // 2 x [64 keys][64 d]
    __shared__ __align__(16) short vls[2 * 4096];     // 2 x [64 d][64 keys]
    __shared__ __align__(16) short pls[4 * 2304];     // per-wave 32 rows x 72
    const int tid = threadIdx.x, wave = tid >> 6, lane = tid & 63;
    const int l15 = lane & 15, lhi = lane >> 4;
    const int b = blockIdx.y >> 4, h = blockIdx.y & 15;
    const int q0 = blockIdx.x * 128 + wave * 32;

    // Q fragments (2 frags x 2 k-halves)
    bf16x8 qf[2][2];
#pragma unroll
    for (int f = 0; f < 2; ++f) {
        const short* qp = Q + ((size_t)(b * 1024 + q0 + f * 16 + l15) * 1024 + h * 64);
        qf[f][0] = *(const bf16x8*)(qp + lhi * 8);
        qf[f][1] = *(const bf16x8*)(qp + 32 + lhi * 8);
    }

    f32x4 oa[2][4];
#pragma unroll
    for (int f = 0; f < 2; ++f)
#pragma unroll
        for (int c = 0; c < 4; ++c) oa[f][c] = (f32x4){0.f, 0.f, 0.f, 0.f};
    float m[8], lsum[8];
#pragma unroll
    for (int i = 0; i < 8; ++i) { m[i] = -1e30f; lsum[i] = 0.f; }

    // staging geometry: per wave 2 insts for K, 2 for V; inst i covers
    // rows wave*16 + i*8 + (lane>>3); within-row 16B chunk (lane&7),
    // source pre-swizzled by ((row&7)<<4) = ((lane>>3)<<4).
    const int srow = (lane >> 3);                         // row&7 within stripe
    const int scol = (((lane & 7) ^ srow) << 4);          // swizzled byte col
    const int r0k = wave * 16 + srow;                     // inst0 row
    const int r1k = wave * 16 + 8 + srow;                 // inst1 row
    const char* kc0 = (const char*)(Kb + ((size_t)(b * 2048 + r0k) * 1024 + h * 64)) + scol;
    const char* kc1 = (const char*)(Kb + ((size_t)(b * 2048 + r1k) * 1024 + h * 64)) + scol;
    const char* vc0 = (const char*)(VT + ((size_t)((b * 16 + h) * 64 + r0k) * 2048)) + scol;
    const char* vc1 = (const char*)(VT + ((size_t)((b * 16 + h) * 64 + r1k) * 2048)) + scol;
    const int kdst0 = wave * 1024, kdst1 = wave * 1024 + 512;   // shorts

    // prologue: stage tile 0 into buf 0
    gload16(kc0, (char*)&kls[kdst0]);
    gload16(kc1, (char*)&kls[kdst1]);
    gload16(vc0, (char*)&vls[kdst0]);
    gload16(vc1, (char*)&vls[kdst1]);
    kc0 += 131072; kc1 += 131072; vc0 += 128; vc1 += 128;
    __syncthreads();

    short* plw = pls + wave * 2304;
    int cur = 0;

    for (int t = 0; t < 32; ++t) {
        const int nxt = cur ^ 1;
        if (t < 31) {   // stage next tile
            gload16(kc0, (char*)&kls[nxt * 4096 + kdst0]);
            gload16(kc1, (char*)&kls[nxt * 4096 + kdst1]);
            gload16(vc0, (char*)&vls[nxt * 4096 + kdst0]);
            gload16(vc1, (char*)&vls[nxt * 4096 + kdst1]);
            kc0 += 131072; kc1 += 131072; vc0 += 128; vc1 += 128;
        }
        const char* kcur = (const char*)&kls[cur * 4096];
        const char* vcur = (const char*)&vls[cur * 4096];

        // QK^T: 64 keys x 32 q-rows
        f32x4 s[2][4];
#pragma unroll
        for (int g = 0; g < 4; ++g) {
            const int key = g * 16 + l15;
            const int sw = (key & 7) << 4;
            const bf16x8 kf0 = *(const bf16x8*)(kcur + key * 128 + ((lhi * 16) ^ sw));
            const bf16x8 kf1 = *(const bf16x8*)(kcur + key * 128 + ((64 + lhi * 16) ^ sw));
            s[0][g] = mfma16(qf[0][0], kf0, (f32x4){0.f, 0.f, 0.f, 0.f});
            s[0][g] = mfma16(qf[0][1], kf1, s[0][g]);
            s[1][g] = mfma16(qf[1][0], kf0, (f32x4){0.f, 0.f, 0.f, 0.f});
            s[1][g] = mfma16(qf[1][1], kf1, s[1][g]);
        }

        // online softmax (row max shared over 16 lanes; sum kept per-lane)
#pragma unroll
        for (int f = 0; f < 2; ++f)
#pragma unroll
            for (int r = 0; r < 4; ++r) {
                const int mi = f * 4 + r;
                float vm = fmaxf(fmaxf(s[f][0][r], s[f][1][r]),
                                 fmaxf(s[f][2][r], s[f][3][r]));
#pragma unroll
                for (int off = 1; off < 16; off <<= 1)
                    vm = fmaxf(vm, __shfl_xor(vm, off, 16));
                const float nm = fmaxf(m[mi], vm);
                const float sc = __expf(m[mi] - nm);
                m[mi] = nm;
                float ps = 0.f;
                const int prow = (f * 16 + lhi * 4 + r) * 72;
#pragma unroll
                for (int g = 0; g < 4; ++g) {
                    const float p = __expf(s[f][g][r] - nm);
                    ps += p;
                    plw[prow + g * 16 + l15] = f2b(p);
                }
                lsum[mi] = lsum[mi] * sc + ps;
                oa[f][0][r] *= sc; oa[f][1][r] *= sc;
                oa[f][2][r] *= sc; oa[f][3][r] *= sc;
            }

        // PV: read V fragments once, P fragments per q-frag
        bf16x8 vb[4][2];
#pragma unroll
        for (int ct = 0; ct < 4; ++ct) {
            const int d = ct * 16 + l15;
            const int sw = (d & 7) << 4;
            vb[ct][0] = *(const bf16x8*)(vcur + d * 128 + ((lhi * 16) ^ sw));
            vb[ct][1] = *(const bf16x8*)(vcur + d * 128 + ((64 + lhi * 16) ^ sw));
        }
#pragma unroll
        for (int f = 0; f < 2; ++f) {
            const bf16x8 pa0 = *(const bf16x8*)&plw[(f * 16 + l15) * 72 + lhi * 8];
            const bf16x8 pa1 = *(const bf16x8*)&plw[(f * 16 + l15) * 72 + 32 + lhi * 8];
#pragma unroll
            for (int ct = 0; ct < 4; ++ct) {
                oa[f][ct] = mfma16(pa0, vb[ct][0], oa[f][ct]);
                oa[f][ct] = mfma16(pa1, vb[ct][1], oa[f][ct]);
            }
        }
        __syncthreads();
        cur = nxt;
    }

    // epilogue: reduce lsum across the 16-lane key groups, normalize, store
#pragma unroll
    for (int i = 0; i < 8; ++i) {
#pragma unroll
        for (int off = 1; off < 16; off <<= 1)
            lsum[i] += __shfl_xor(lsum[i], off, 16);
        lsum[i] = 1.f / lsum[i];
    }
#pragma unroll
    for (int f = 0; f < 2; ++f)
#pragma unroll
        for (int r = 0; r < 4; ++r) {
            const int qrow = q0 + f * 16 + lhi * 4 + r;
            short* cp = ctx + ((size_t)(b * 1024 + qrow) * 1024 + h * 64);
            const float inv = lsum[f * 4 + r];
#pragma unroll
            for (int ct = 0; ct < 4; ++ct)
                cp[ct * 16 + l15] = f2b(oa[f][ct][r] * inv);
        }
}

// ------------------------------- launcher ----------------------------------

extern "C" void kernel_launch(void* const* d_in, const int* in_sizes, int n_in,
                              void* d_out, int out_size, void* d_ws, size_t ws_size,
                              hipStream_t stream) {
    const float* tgt  = (const float*)d_in[0];
    const float* emb  = (const float*)d_in[1];
    const float* ln_g = (const float*)d_in[2];
    const float* ln_b = (const float*)d_in[3];
    const float* wq = (const float*)d_in[4];  const float* bq = (const float*)d_in[5];
    const float* wk = (const float*)d_in[6];  const float* bk = (const float*)d_in[7];
    const float* wv = (const float*)d_in[8];  const float* bv = (const float*)d_in[9];
    const float* wo = (const float*)d_in[10]; const float* bo = (const float*)d_in[11];
    const float* w1 = (const float*)d_in[12]; const float* b1 = (const float*)d_in[13];
    const float* w2 = (const float*)d_in[14]; const float* b2 = (const float*)d_in[15];

    char* ws = (char*)d_ws;
    const size_t MB = 1024 * 1024;
    short* wqT  = (short*)(ws + 0 * MB);
    short* wkT  = (short*)(ws + 2 * MB);
    short* wvT  = (short*)(ws + 4 * MB);
    short* woT  = (short*)(ws + 6 * MB);
    short* w1T  = (short*)(ws + 8 * MB);    // 8MB
    short* w2T  = (short*)(ws + 16 * MB);   // 8MB
    float* tgt2 = (float*)(ws + 24 * MB);   // 16MB (lifetime disjoint from embB)
    short* embB = (short*)(ws + 40 * MB);   // 16MB (dead after K/V GEMMs)
    short* qn   = (short*)(ws + 56 * MB);   // 8MB (reused as hn)
    short* qbuf = (short*)(ws + 64 * MB);   // 8MB
    short* kbuf = (short*)(ws + 72 * MB);   // 16MB
    short* vbuf = (short*)(ws + 88 * MB);   // 16MB
    short* VT   = (short*)(ws + 104 * MB);  // 16MB
    short* ctx  = (short*)(ws + 120 * MB);  // 8MB
    short* h1   = (short*)(ws + 64 * MB);   // 32MB, reuses q/k/v region (dead by MLP)
    float* outp = (float*)d_out;

    const dim3 tb(32, 8);
    // weights -> bf16 transposed
    transpose_f2b<<<dim3(32, 32), tb, 0, stream>>>(wq, wqT, 1024, 1024);
    transpose_f2b<<<dim3(32, 32), tb, 0, stream>>>(wk, wkT, 1024, 1024);
    transpose_f2b<<<dim3(32, 32), tb, 0, stream>>>(wv, wvT, 1024, 1024);
    transpose_f2b<<<dim3(32, 32), tb, 0, stream>>>(wo, woT, 1024, 1024);
    transpose_f2b<<<dim3(128, 32), tb, 0, stream>>>(w1, w1T, 1024, 4096);
    transpose_f2b<<<dim3(32, 128), tb, 0, stream>>>(w2, w2T, 4096, 1024);
    // emb -> bf16
    conv_f2b<<<8192, 256, 0, stream>>>(emb, embB, 8192 * 1024 / 4);
    // qn = LN(tgt)
    ln_bf16<<<4096, 256, 0, stream>>>(tgt, ln_g, ln_b, qn);
    // q = (qn@wq + bq)/8 ; k/v = emb@w + b
    gemm_bt<1, 0, 0, 0><<<dim3(32, 8), 256, 0, stream>>>(qn, wqT, bq, nullptr, qbuf, 4096, 1024, 1024, 0.125f);
    gemm_bt<1, 0, 0, 0><<<dim3(64, 8), 256, 0, stream>>>(embB, wkT, bk, nullptr, kbuf, 8192, 1024, 1024, 1.f);
    gemm_bt<1, 0, 0, 0><<<dim3(64, 8), 256, 0, stream>>>(embB, wvT, bv, nullptr, vbuf, 8192, 1024, 1024, 1.f);
    transpose_v<<<dim3(64, 2, 64), tb, 0, stream>>>(vbuf, VT);
    // attention (QBLK=128, KVBLK=64, LDS double-buffered)
    attn_flash<<<dim3(8, 64), 256, 0, stream>>>(qbuf, kbuf, VT, ctx);
    // tgt2 = tgt + ctx@wo + bo
    gemm_bt<1, 1, 0, 1><<<dim3(32, 8), 256, 0, stream>>>(ctx, woT, bo, tgt, tgt2, 4096, 1024, 1024, 1.f);
    // hn = LN(tgt2)
    ln_bf16<<<4096, 256, 0, stream>>>(tgt2, ln_g, ln_b, qn);
    // h1 = gelu(hn@w1 + b1)
    gemm_bt<1, 0, 1, 0><<<dim3(32, 32), 256, 0, stream>>>(qn, w1T, b1, nullptr, h1, 4096, 4096, 1024, 1.f);
    // out = tgt2 + h1@w2 + b2
    gemm_bt<1, 1, 0, 1><<<dim3(32, 8), 256, 0, stream>>>(h1, w2T, b2, tgt2, outp, 4096, 1024, 4096, 1.f);

    (void)in_sizes; (void)n_in; (void)out_size; (void)ws_size;
}

// Round 6
// 526.669 us; speedup vs baseline: 1.2993x; 1.0697x over previous
//
#include <hip/hip_runtime.h>
#include <cstdint>
#include <cstddef>

// ---------------------------------------------------------------------------
// DecoderBlock (cross-attn + MLP), MI355X gfx950.
// fp32 in/out, bf16 MFMA compute.
// B=4, Nq=1024, Nk=2048, DIM=1024, H=16, HD=64, HID=4096.
// ---------------------------------------------------------------------------

typedef __attribute__((ext_vector_type(8))) short bf16x8;
typedef __attribute__((ext_vector_type(4))) float f32x4;

__device__ __forceinline__ short f2b(float f) {
    unsigned u = __builtin_bit_cast(unsigned, f);
    unsigned r = (u + 0x7FFFu + ((u >> 16) & 1u)) >> 16;   // RNE
    return (short)r;
}

__device__ __forceinline__ f32x4 mfma16(bf16x8 a, bf16x8 b, f32x4 c) {
    return __builtin_amdgcn_mfma_f32_16x16x32_bf16(a, b, c, 0, 0, 0);
}

__device__ __forceinline__ void gload16(const void* g, void* l) {
    __builtin_amdgcn_global_load_lds(
        (const __attribute__((address_space(1))) unsigned int*)g,
        (__attribute__((address_space(3))) unsigned int*)l, 16, 0, 0);
}

// ------------------------------- prep kernels ------------------------------

// fp32 [R][C] -> bf16 [C][R]
__global__ __launch_bounds__(256) void transpose_f2b(
    const float* __restrict__ in, short* __restrict__ out, int R, int C) {
    __shared__ float tile[32][33];
    const int c0 = blockIdx.x * 32, r0 = blockIdx.y * 32;
    const int tx = threadIdx.x, ty = threadIdx.y;   // (32,8)
#pragma unroll
    for (int i = 0; i < 4; ++i)
        tile[ty + 8 * i][tx] = in[(size_t)(r0 + ty + 8 * i) * C + c0 + tx];
    __syncthreads();
#pragma unroll
    for (int i = 0; i < 4; ++i)
        out[(size_t)(c0 + ty + 8 * i) * R + r0 + tx] = f2b(tile[tx][ty + 8 * i]);
}

// fp32 -> bf16 flat (n4 = count/4)
__global__ __launch_bounds__(256) void conv_f2b(
    const float* __restrict__ in, short* __restrict__ out, int n4) {
    int i = blockIdx.x * 256 + threadIdx.x;
    if (i < n4) {
        float4 v = reinterpret_cast<const float4*>(in)[i];
        short4 o;
        o.x = f2b(v.x); o.y = f2b(v.y); o.z = f2b(v.z); o.w = f2b(v.w);
        reinterpret_cast<short4*>(out)[i] = o;
    }
}

// LayerNorm over D=1024, fp32 in -> bf16 out. One row per block (256 thr).
__global__ __launch_bounds__(256) void ln_bf16(
    const float* __restrict__ x, const float* __restrict__ g,
    const float* __restrict__ bb, short* __restrict__ out) {
    const int row = blockIdx.x, tid = threadIdx.x;
    float4 v = reinterpret_cast<const float4*>(x + (size_t)row * 1024)[tid];
    float s = v.x + v.y + v.z + v.w;
    float q = v.x * v.x + v.y * v.y + v.z * v.z + v.w * v.w;
#pragma unroll
    for (int off = 32; off; off >>= 1) {
        s += __shfl_down(s, off);
        q += __shfl_down(q, off);
    }
    __shared__ float ss[4], sq[4];
    const int wave = tid >> 6, lane = tid & 63;
    if (lane == 0) { ss[wave] = s; sq[wave] = q; }
    __syncthreads();
    s = ss[0] + ss[1] + ss[2] + ss[3];
    q = sq[0] + sq[1] + sq[2] + sq[3];
    const float mu = s * (1.f / 1024.f);
    const float var = q * (1.f / 1024.f) - mu * mu;
    const float rs = rsqrtf(var + 1e-5f);
    float4 gg = reinterpret_cast<const float4*>(g)[tid];
    float4 bv = reinterpret_cast<const float4*>(bb)[tid];
    short4 o;
    o.x = f2b((v.x - mu) * rs * gg.x + bv.x);
    o.y = f2b((v.y - mu) * rs * gg.y + bv.y);
    o.z = f2b((v.z - mu) * rs * gg.z + bv.z);
    o.w = f2b((v.w - mu) * rs * gg.w + bv.w);
    reinterpret_cast<short4*>(out + (size_t)row * 1024)[tid] = o;
}

// vbuf bf16 [B][2048][H*64] -> VT bf16 [B][H][64][2048]
__global__ __launch_bounds__(256) void transpose_v(
    const short* __restrict__ vbuf, short* __restrict__ VT) {
    __shared__ short t[32][33];
    const int b = blockIdx.z >> 4, h = blockIdx.z & 15;
    const int n0 = blockIdx.x * 32, d0 = blockIdx.y * 32;
    const int tx = threadIdx.x, ty = threadIdx.y;   // (32,8)
#pragma unroll
    for (int i = 0; i < 4; ++i)
        t[ty + 8 * i][tx] =
            vbuf[(size_t)(b * 2048 + n0 + ty + 8 * i) * 1024 + h * 64 + d0 + tx];
    __syncthreads();
#pragma unroll
    for (int i = 0; i < 4; ++i)
        VT[(size_t)((b * 16 + h) * 64 + d0 + ty + 8 * i) * 2048 + n0 + tx] =
            t[tx][ty + 8 * i];
}

// ------------------------------- GEMM --------------------------------------
// C[M,N] = act( (A[M,K] @ BT[N,K]^T + bias) * scale ) + resid
// A,BT bf16 row-major-along-K. 128x128 tile, 4 waves, BK=64 (2x32 halves:
// each half keeps the contiguous conflict-free BK=32 LDS layout; one
// barrier pair per 64 K => 32 MFMA + 16 staging loads in flight per sync).
template <int BIAS, int RESID, int GELU, int OUTF>
__global__ __launch_bounds__(256) void gemm_bt(
    const short* __restrict__ A, const short* __restrict__ BT,
    const float* __restrict__ bias, const float* __restrict__ resid,
    void* __restrict__ out, int M, int N, int K, float scale) {
    __shared__ __align__(16) short As[2][128 * 32];
    __shared__ __align__(16) short Bs[2][128 * 32];
    const int tid = threadIdx.x;
    const int wave = tid >> 6, lane = tid & 63;
    const int l15 = lane & 15, lhi = lane >> 4;
    const int bm = blockIdx.x, bn = blockIdx.y;
    const int wm = (wave >> 1) * 64, wn = (wave & 1) * 64;

    f32x4 acc[4][4];
#pragma unroll
    for (int i = 0; i < 4; ++i)
#pragma unroll
        for (int j = 0; j < 4; ++j) acc[i][j] = (f32x4){0.f, 0.f, 0.f, 0.f};

    // per-lane staging geometry (same for both halves)
    const int ob0 = wave * 2048;                 // wave-uniform LDS byte base
    const int o0 = ob0 + lane * 16;
    const int row0 = o0 >> 6, kb0 = o0 & 63;     // 64B per 32-elem row
    const int ob1 = wave * 2048 + 1024;
    const int o1 = ob1 + lane * 16;
    const int row1 = o1 >> 6, kb1 = o1 & 63;

    for (int k0 = 0; k0 < K; k0 += 64) {
#pragma unroll
        for (int hh = 0; hh < 2; ++hh) {
            const int kc = k0 + hh * 32;
            gload16((const char*)A + ((size_t)(bm * 128 + row0) * K + kc) * 2 + kb0,
                    (char*)As[hh] + ob0);
            gload16((const char*)A + ((size_t)(bm * 128 + row1) * K + kc) * 2 + kb1,
                    (char*)As[hh] + ob1);
            gload16((const char*)BT + ((size_t)(bn * 128 + row0) * K + kc) * 2 + kb0,
                    (char*)Bs[hh] + ob0);
            gload16((const char*)BT + ((size_t)(bn * 128 + row1) * K + kc) * 2 + kb1,
                    (char*)Bs[hh] + ob1);
        }
        __syncthreads();
#pragma unroll
        for (int hh = 0; hh < 2; ++hh) {
            bf16x8 af[4], bfr[4];
#pragma unroll
            for (int t = 0; t < 4; ++t) {
                af[t]  = *(const bf16x8*)&As[hh][(wm + t * 16 + l15) * 32 + lhi * 8];
                bfr[t] = *(const bf16x8*)&Bs[hh][(wn + t * 16 + l15) * 32 + lhi * 8];
            }
#pragma unroll
            for (int mt = 0; mt < 4; ++mt)
#pragma unroll
                for (int nt = 0; nt < 4; ++nt)
                    acc[mt][nt] = mfma16(af[mt], bfr[nt], acc[mt][nt]);
        }
        __syncthreads();
    }

#pragma unroll
    for (int mt = 0; mt < 4; ++mt)
#pragma unroll
        for (int nt = 0; nt < 4; ++nt)
#pragma unroll
            for (int r = 0; r < 4; ++r) {
                const int row = bm * 128 + wm + mt * 16 + lhi * 4 + r;
                const int col = bn * 128 + wn + nt * 16 + l15;
                float v = acc[mt][nt][r];
                if (BIAS) v += bias[col];
                v *= scale;
                if (GELU) v = 0.5f * v * (1.f + erff(v * 0.70710678118f));
                if (RESID) v += resid[(size_t)row * N + col];
                if (OUTF)
                    ((float*)out)[(size_t)row * N + col] = v;
                else
                    ((short*)out)[(size_t)row * N + col] = f2b(v);
            }
}

// ---------------------------- flash attention ------------------------------
// Q: bf16 [B*1024][1024] (pre-scaled by 1/8), K: bf16 [B*2048][1024],
// VT: bf16 [B][H][64][2048], ctx out: bf16 [B*1024][1024].
// grid (Nq/64, B*H), 4 waves; wave owns 16 q-rows. KVBLK=64, double-buffered
// LDS K/V (XOR-swizzled rows). P buffer stride-64 + chunk-XOR swizzle.
// LDS = 16+16+8 = 40KB -> 4 blocks/CU; grid 1024 = 4/CU -> 16 waves/CU.
__global__ __launch_bounds__(256) void attn_flash(
    const short* __restrict__ Q, const short* __restrict__ Kb,
    const short* __restrict__ VT, short* __restrict__ ctx) {
    __shared__ __align__(16) short kls[2 * 4096];     // 2 x [64 keys][64 d]
    __shared__ __align__(16) short vls[2 * 4096];     // 2 x [64 d][64 keys]
    __shared__ __align__(16) short pls[4 * 1024];     // per-wave 16 rows x 64
    const int tid = threadIdx.x, wave = tid >> 6, lane = tid & 63;
    const int l15 = lane & 15, lhi = lane >> 4;
    const int b = blockIdx.y >> 4, h = blockIdx.y & 15;
    const int q0 = blockIdx.x * 64 + wave * 16;

    const short* qp = Q + ((size_t)(b * 1024 + q0 + l15) * 1024 + h * 64);
    const bf16x8 qf0 = *(const bf16x8*)(qp + lhi * 8);
    const bf16x8 qf1 = *(const bf16x8*)(qp + 32 + lhi * 8);

    f32x4 oa[4];
#pragma unroll
    for (int c = 0; c < 4; ++c) oa[c] = (f32x4){0.f, 0.f, 0.f, 0.f};
    float m[4] = {-1e30f, -1e30f, -1e30f, -1e30f};
    float lsum[4] = {0.f, 0.f, 0.f, 0.f};

    // staging: per wave 2 insts K + 2 insts V; inst covers 8 rows x 128B,
    // source pre-swizzled by ((row&7)<<4) so LDS stays linear (rule 21).
    const int srow = (lane >> 3);                         // row&7 within stripe
    const int scol = (((lane & 7) ^ srow) << 4);          // swizzled byte col
    const int r0k = wave * 16 + srow;
    const int r1k = wave * 16 + 8 + srow;
    const char* kc0 = (const char*)(Kb + ((size_t)(b * 2048 + r0k) * 1024 + h * 64)) + scol;
    const char* kc1 = (const char*)(Kb + ((size_t)(b * 2048 + r1k) * 1024 + h * 64)) + scol;
    const char* vc0 = (const char*)(VT + ((size_t)((b * 16 + h) * 64 + r0k) * 2048)) + scol;
    const char* vc1 = (const char*)(VT + ((size_t)((b * 16 + h) * 64 + r1k) * 2048)) + scol;
    const int kdst0 = wave * 1024, kdst1 = wave * 1024 + 512;   // shorts

    gload16(kc0, (char*)&kls[kdst0]);
    gload16(kc1, (char*)&kls[kdst1]);
    gload16(vc0, (char*)&vls[kdst0]);
    gload16(vc1, (char*)&vls[kdst1]);
    kc0 += 131072; kc1 += 131072; vc0 += 128; vc1 += 128;
    __syncthreads();

    short* plw = pls + wave * 1024;
    int cur = 0;

    for (int t = 0; t < 32; ++t) {
        const int nxt = cur ^ 1;
        if (t < 31) {
            gload16(kc0, (char*)&kls[nxt * 4096 + kdst0]);
            gload16(kc1, (char*)&kls[nxt * 4096 + kdst1]);
            gload16(vc0, (char*)&vls[nxt * 4096 + kdst0]);
            gload16(vc1, (char*)&vls[nxt * 4096 + kdst1]);
            kc0 += 131072; kc1 += 131072; vc0 += 128; vc1 += 128;
        }
        const char* kcur = (const char*)&kls[cur * 4096];
        const char* vcur = (const char*)&vls[cur * 4096];

        // QK^T: 64 keys x 16 q-rows
        f32x4 s[4];
        __builtin_amdgcn_s_setprio(1);
#pragma unroll
        for (int g = 0; g < 4; ++g) {
            const int key = g * 16 + l15;
            const int sw = (key & 7) << 4;
            const bf16x8 kf0 = *(const bf16x8*)(kcur + key * 128 + ((lhi * 16) ^ sw));
            const bf16x8 kf1 = *(const bf16x8*)(kcur + key * 128 + ((64 + lhi * 16) ^ sw));
            s[g] = mfma16(qf0, kf0, (f32x4){0.f, 0.f, 0.f, 0.f});
            s[g] = mfma16(qf1, kf1, s[g]);
        }
        __builtin_amdgcn_s_setprio(0);

        // online softmax: row max over 16 lanes; sums per-lane (epilogue reduce)
#pragma unroll
        for (int r = 0; r < 4; ++r) {
            float vm = fmaxf(fmaxf(s[0][r], s[1][r]), fmaxf(s[2][r], s[3][r]));
#pragma unroll
            for (int off = 1; off < 16; off <<= 1)
                vm = fmaxf(vm, __shfl_xor(vm, off, 16));
            const float nm = fmaxf(m[r], vm);
            const float sc = __expf(m[r] - nm);
            m[r] = nm;
            const float p0 = __expf(s[0][r] - nm);
            const float p1 = __expf(s[1][r] - nm);
            const float p2 = __expf(s[2][r] - nm);
            const float p3 = __expf(s[3][r] - nm);
            lsum[r] = lsum[r] * sc + ((p0 + p1) + (p2 + p3));
            unsigned pk01, pk23;
            asm("v_cvt_pk_bf16_f32 %0, %1, %2" : "=v"(pk01) : "v"(p0), "v"(p1));
            asm("v_cvt_pk_bf16_f32 %0, %1, %2" : "=v"(pk23) : "v"(p2), "v"(p3));
            const int prow = lhi * 4 + r;
            char* prb = (char*)plw + prow * 128;
            const int swp = (prow & 7) << 4;
            *(short*)(prb + ((l15 * 2) ^ swp))      = (short)pk01;
            *(short*)(prb + ((32 + l15 * 2) ^ swp)) = (short)(pk01 >> 16);
            *(short*)(prb + ((64 + l15 * 2) ^ swp)) = (short)pk23;
            *(short*)(prb + ((96 + l15 * 2) ^ swp)) = (short)(pk23 >> 16);
            oa[0][r] *= sc; oa[1][r] *= sc; oa[2][r] *= sc; oa[3][r] *= sc;
        }

        // PV
        bf16x8 vb[4][2];
#pragma unroll
        for (int ct = 0; ct < 4; ++ct) {
            const int d = ct * 16 + l15;
            const int sw = (d & 7) << 4;
            vb[ct][0] = *(const bf16x8*)(vcur + d * 128 + ((lhi * 16) ^ sw));
            vb[ct][1] = *(const bf16x8*)(vcur + d * 128 + ((64 + lhi * 16) ^ sw));
        }
        const char* prr = (const char*)plw + l15 * 128;
        const int swr = (l15 & 7) << 4;
        const bf16x8 pa0 = *(const bf16x8*)(prr + ((lhi * 16) ^ swr));
        const bf16x8 pa1 = *(const bf16x8*)(prr + ((64 + lhi * 16) ^ swr));
        __builtin_amdgcn_s_setprio(1);
#pragma unroll
        for (int ct = 0; ct < 4; ++ct) {
            oa[ct] = mfma16(pa0, vb[ct][0], oa[ct]);
            oa[ct] = mfma16(pa1, vb[ct][1], oa[ct]);
        }
        __builtin_amdgcn_s_setprio(0);
        __syncthreads();
        cur = nxt;
    }

    // epilogue: reduce lsum across the 16-lane key groups, normalize, store
#pragma unroll
    for (int i = 0; i < 4; ++i) {
#pragma unroll
        for (int off = 1; off < 16; off <<= 1)
            lsum[i] += __shfl_xor(lsum[i], off, 16);
        lsum[i] = 1.f / lsum[i];
    }
#pragma unroll
    for (int r = 0; r < 4; ++r) {
        const int qrow = q0 + lhi * 4 + r;
        short* cp = ctx + ((size_t)(b * 1024 + qrow) * 1024 + h * 64);
        const float inv = lsum[r];
#pragma unroll
        for (int ct = 0; ct < 4; ++ct)
            cp[ct * 16 + l15] = f2b(oa[ct][r] * inv);
    }
}

// ------------------------------- launcher ----------------------------------

extern "C" void kernel_launch(void* const* d_in, const int* in_sizes, int n_in,
                              void* d_out, int out_size, void* d_ws, size_t ws_size,
                              hipStream_t stream) {
    const float* tgt  = (const float*)d_in[0];
    const float* emb  = (const float*)d_in[1];
    const float* ln_g = (const float*)d_in[2];
    const float* ln_b = (const float*)d_in[3];
    const float* wq = (const float*)d_in[4];  const float* bq = (const float*)d_in[5];
    const float* wk = (const float*)d_in[6];  const float* bk = (const float*)d_in[7];
    const float* wv = (const float*)d_in[8];  const float* bv = (const float*)d_in[9];
    const float* wo = (const float*)d_in[10]; const float* bo = (const float*)d_in[11];
    const float* w1 = (const float*)d_in[12]; const float* b1 = (const float*)d_in[13];
    const float* w2 = (const float*)d_in[14]; const float* b2 = (const float*)d_in[15];

    char* ws = (char*)d_ws;
    const size_t MB = 1024 * 1024;
    short* wqT  = (short*)(ws + 0 * MB);
    short* wkT  = (short*)(ws + 2 * MB);
    short* wvT  = (short*)(ws + 4 * MB);
    short* woT  = (short*)(ws + 6 * MB);
    short* w1T  = (short*)(ws + 8 * MB);    // 8MB
    short* w2T  = (short*)(ws + 16 * MB);   // 8MB
    float* tgt2 = (float*)(ws + 24 * MB);   // 16MB (lifetime disjoint from embB)
    short* embB = (short*)(ws + 40 * MB);   // 16MB (dead after K/V GEMMs)
    short* qn   = (short*)(ws + 56 * MB);   // 8MB (reused as hn)
    short* qbuf = (short*)(ws + 64 * MB);   // 8MB
    short* kbuf = (short*)(ws + 72 * MB);   // 16MB
    short* vbuf = (short*)(ws + 88 * MB);   // 16MB
    short* VT   = (short*)(ws + 104 * MB);  // 16MB
    short* ctx  = (short*)(ws + 120 * MB);  // 8MB
    short* h1   = (short*)(ws + 64 * MB);   // 32MB, reuses q/k/v region (dead by MLP)
    float* outp = (float*)d_out;

    const dim3 tb(32, 8);
    // weights -> bf16 transposed
    transpose_f2b<<<dim3(32, 32), tb, 0, stream>>>(wq, wqT, 1024, 1024);
    transpose_f2b<<<dim3(32, 32), tb, 0, stream>>>(wk, wkT, 1024, 1024);
    transpose_f2b<<<dim3(32, 32), tb, 0, stream>>>(wv, wvT, 1024, 1024);
    transpose_f2b<<<dim3(32, 32), tb, 0, stream>>>(wo, woT, 1024, 1024);
    transpose_f2b<<<dim3(128, 32), tb, 0, stream>>>(w1, w1T, 1024, 4096);
    transpose_f2b<<<dim3(32, 128), tb, 0, stream>>>(w2, w2T, 4096, 1024);
    // emb -> bf16
    conv_f2b<<<8192, 256, 0, stream>>>(emb, embB, 8192 * 1024 / 4);
    // qn = LN(tgt)
    ln_bf16<<<4096, 256, 0, stream>>>(tgt, ln_g, ln_b, qn);
    // q = (qn@wq + bq)/8 ; k/v = emb@w + b
    gemm_bt<1, 0, 0, 0><<<dim3(32, 8), 256, 0, stream>>>(qn, wqT, bq, nullptr, qbuf, 4096, 1024, 1024, 0.125f);
    gemm_bt<1, 0, 0, 0><<<dim3(64, 8), 256, 0, stream>>>(embB, wkT, bk, nullptr, kbuf, 8192, 1024, 1024, 1.f);
    gemm_bt<1, 0, 0, 0><<<dim3(64, 8), 256, 0, stream>>>(embB, wvT, bv, nullptr, vbuf, 8192, 1024, 1024, 1.f);
    transpose_v<<<dim3(64, 2, 64), tb, 0, stream>>>(vbuf, VT);
    // attention (QBLK=64, KVBLK=64, LDS double-buffered)
    attn_flash<<<dim3(16, 64), 256, 0, stream>>>(qbuf, kbuf, VT, ctx);
    // tgt2 = tgt + ctx@wo + bo
    gemm_bt<1, 1, 0, 1><<<dim3(32, 8), 256, 0, stream>>>(ctx, woT, bo, tgt, tgt2, 4096, 1024, 1024, 1.f);
    // hn = LN(tgt2)
    ln_bf16<<<4096, 256, 0, stream>>>(tgt2, ln_g, ln_b, qn);
    // h1 = gelu(hn@w1 + b1)
    gemm_bt<1, 0, 1, 0><<<dim3(32, 32), 256, 0, stream>>>(qn, w1T, b1, nullptr, h1, 4096, 4096, 1024, 1.f);
    // out = tgt2 + h1@w2 + b2
    gemm_bt<1, 1, 0, 1><<<dim3(32, 8), 256, 0, stream>>>(h1, w2T, b2, tgt2, outp, 4096, 1024, 4096, 1.f);

    (void)in_sizes; (void)n_in; (void)out_size; (void)ws_size;
}

// Round 8
// 504.090 us; speedup vs baseline: 1.3575x; 1.0448x over previous
//
#include <hip/hip_runtime.h>
#include <cstdint>
#include <cstddef>

// ---------------------------------------------------------------------------
// DecoderBlock (cross-attn + MLP), MI355X gfx950.
// fp32 in/out, bf16 MFMA compute.
// B=4, Nq=1024, Nk=2048, DIM=1024, H=16, HD=64, HID=4096.
// ---------------------------------------------------------------------------

typedef __attribute__((ext_vector_type(8))) short bf16x8;
typedef __attribute__((ext_vector_type(4))) float f32x4;

__device__ __forceinline__ short f2b(float f) {
    unsigned u = __builtin_bit_cast(unsigned, f);
    unsigned r = (u + 0x7FFFu + ((u >> 16) & 1u)) >> 16;   // RNE
    return (short)r;
}

__device__ __forceinline__ f32x4 mfma16(bf16x8 a, bf16x8 b, f32x4 c) {
    return __builtin_amdgcn_mfma_f32_16x16x32_bf16(a, b, c, 0, 0, 0);
}

__device__ __forceinline__ void gload16(const void* g, void* l) {
    __builtin_amdgcn_global_load_lds(
        (const __attribute__((address_space(1))) unsigned int*)g,
        (__attribute__((address_space(3))) unsigned int*)l, 16, 0, 0);
}

// ------------------------------- prep kernels ------------------------------

// fp32 [R][C] -> bf16 [C][R]
__global__ __launch_bounds__(256) void transpose_f2b(
    const float* __restrict__ in, short* __restrict__ out, int R, int C) {
    __shared__ float tile[32][33];
    const int c0 = blockIdx.x * 32, r0 = blockIdx.y * 32;
    const int tx = threadIdx.x, ty = threadIdx.y;   // (32,8)
#pragma unroll
    for (int i = 0; i < 4; ++i)
        tile[ty + 8 * i][tx] = in[(size_t)(r0 + ty + 8 * i) * C + c0 + tx];
    __syncthreads();
#pragma unroll
    for (int i = 0; i < 4; ++i)
        out[(size_t)(c0 + ty + 8 * i) * R + r0 + tx] = f2b(tile[tx][ty + 8 * i]);
}

// fp32 -> bf16 flat (n4 = count/4)
__global__ __launch_bounds__(256) void conv_f2b(
    const float* __restrict__ in, short* __restrict__ out, int n4) {
    int i = blockIdx.x * 256 + threadIdx.x;
    if (i < n4) {
        float4 v = reinterpret_cast<const float4*>(in)[i];
        short4 o;
        o.x = f2b(v.x); o.y = f2b(v.y); o.z = f2b(v.z); o.w = f2b(v.w);
        reinterpret_cast<short4*>(out)[i] = o;
    }
}

// LayerNorm over D=1024, fp32 in -> bf16 out. One row per block (256 thr).
__global__ __launch_bounds__(256) void ln_bf16(
    const float* __restrict__ x, const float* __restrict__ g,
    const float* __restrict__ bb, short* __restrict__ out) {
    const int row = blockIdx.x, tid = threadIdx.x;
    float4 v = reinterpret_cast<const float4*>(x + (size_t)row * 1024)[tid];
    float s = v.x + v.y + v.z + v.w;
    float q = v.x * v.x + v.y * v.y + v.z * v.z + v.w * v.w;
#pragma unroll
    for (int off = 32; off; off >>= 1) {
        s += __shfl_down(s, off);
        q += __shfl_down(q, off);
    }
    __shared__ float ss[4], sq[4];
    const int wave = tid >> 6, lane = tid & 63;
    if (lane == 0) { ss[wave] = s; sq[wave] = q; }
    __syncthreads();
    s = ss[0] + ss[1] + ss[2] + ss[3];
    q = sq[0] + sq[1] + sq[2] + sq[3];
    const float mu = s * (1.f / 1024.f);
    const float var = q * (1.f / 1024.f) - mu * mu;
    const float rs = rsqrtf(var + 1e-5f);
    float4 gg = reinterpret_cast<const float4*>(g)[tid];
    float4 bv = reinterpret_cast<const float4*>(bb)[tid];
    short4 o;
    o.x = f2b((v.x - mu) * rs * gg.x + bv.x);
    o.y = f2b((v.y - mu) * rs * gg.y + bv.y);
    o.z = f2b((v.z - mu) * rs * gg.z + bv.z);
    o.w = f2b((v.w - mu) * rs * gg.w + bv.w);
    reinterpret_cast<short4*>(out + (size_t)row * 1024)[tid] = o;
}

// vbuf bf16 [B][2048][H*64] -> VT bf16 [B][H][64][2048]
__global__ __launch_bounds__(256) void transpose_v(
    const short* __restrict__ vbuf, short* __restrict__ VT) {
    __shared__ short t[32][33];
    const int b = blockIdx.z >> 4, h = blockIdx.z & 15;
    const int n0 = blockIdx.x * 32, d0 = blockIdx.y * 32;
    const int tx = threadIdx.x, ty = threadIdx.y;   // (32,8)
#pragma unroll
    for (int i = 0; i < 4; ++i)
        t[ty + 8 * i][tx] =
            vbuf[(size_t)(b * 2048 + n0 + ty + 8 * i) * 1024 + h * 64 + d0 + tx];
    __syncthreads();
#pragma unroll
    for (int i = 0; i < 4; ++i)
        VT[(size_t)((b * 16 + h) * 64 + d0 + ty + 8 * i) * 2048 + n0 + tx] =
            t[tx][ty + 8 * i];
}

// ------------------------------- GEMM --------------------------------------
// C[M,N] = act( (A[M,K] @ BT[N,K]^T + bias) * scale ) + resid
// A,BT bf16 row-major-along-K. 128x128 tile, 4 waves, BK=64 (2x32 halves).
template <int BIAS, int RESID, int GELU, int OUTF>
__global__ __launch_bounds__(256) void gemm_bt(
    const short* __restrict__ A, const short* __restrict__ BT,
    const float* __restrict__ bias, const float* __restrict__ resid,
    void* __restrict__ out, int M, int N, int K, float scale) {
    __shared__ __align__(16) short As[2][128 * 32];
    __shared__ __align__(16) short Bs[2][128 * 32];
    const int tid = threadIdx.x;
    const int wave = tid >> 6, lane = tid & 63;
    const int l15 = lane & 15, lhi = lane >> 4;
    const int bm = blockIdx.x, bn = blockIdx.y;
    const int wm = (wave >> 1) * 64, wn = (wave & 1) * 64;

    f32x4 acc[4][4];
#pragma unroll
    for (int i = 0; i < 4; ++i)
#pragma unroll
        for (int j = 0; j < 4; ++j) acc[i][j] = (f32x4){0.f, 0.f, 0.f, 0.f};

    const int ob0 = wave * 2048;                 // wave-uniform LDS byte base
    const int o0 = ob0 + lane * 16;
    const int row0 = o0 >> 6, kb0 = o0 & 63;     // 64B per 32-elem row
    const int ob1 = wave * 2048 + 1024;
    const int o1 = ob1 + lane * 16;
    const int row1 = o1 >> 6, kb1 = o1 & 63;

    for (int k0 = 0; k0 < K; k0 += 64) {
#pragma unroll
        for (int hh = 0; hh < 2; ++hh) {
            const int kc = k0 + hh * 32;
            gload16((const char*)A + ((size_t)(bm * 128 + row0) * K + kc) * 2 + kb0,
                    (char*)As[hh] + ob0);
            gload16((const char*)A + ((size_t)(bm * 128 + row1) * K + kc) * 2 + kb1,
                    (char*)As[hh] + ob1);
            gload16((const char*)BT + ((size_t)(bn * 128 + row0) * K + kc) * 2 + kb0,
                    (char*)Bs[hh] + ob0);
            gload16((const char*)BT + ((size_t)(bn * 128 + row1) * K + kc) * 2 + kb1,
                    (char*)Bs[hh] + ob1);
        }
        __syncthreads();
#pragma unroll
        for (int hh = 0; hh < 2; ++hh) {
            bf16x8 af[4], bfr[4];
#pragma unroll
            for (int t = 0; t < 4; ++t) {
                af[t]  = *(const bf16x8*)&As[hh][(wm + t * 16 + l15) * 32 + lhi * 8];
                bfr[t] = *(const bf16x8*)&Bs[hh][(wn + t * 16 + l15) * 32 + lhi * 8];
            }
#pragma unroll
            for (int mt = 0; mt < 4; ++mt)
#pragma unroll
                for (int nt = 0; nt < 4; ++nt)
                    acc[mt][nt] = mfma16(af[mt], bfr[nt], acc[mt][nt]);
        }
        __syncthreads();
    }

#pragma unroll
    for (int mt = 0; mt < 4; ++mt)
#pragma unroll
        for (int nt = 0; nt < 4; ++nt)
#pragma unroll
            for (int r = 0; r < 4; ++r) {
                const int row = bm * 128 + wm + mt * 16 + lhi * 4 + r;
                const int col = bn * 128 + wn + nt * 16 + l15;
                float v = acc[mt][nt][r];
                if (BIAS) v += bias[col];
                v *= scale;
                if (GELU) v = 0.5f * v * (1.f + erff(v * 0.70710678118f));
                if (RESID) v += resid[(size_t)row * N + col];
                if (OUTF)
                    ((float*)out)[(size_t)row * N + col] = v;
                else
                    ((short*)out)[(size_t)row * N + col] = f2b(v);
            }
}

// ---------------------------- flash attention ------------------------------
// Q: bf16 [B*1024][1024] (pre-scaled by 1/8), K: bf16 [B*2048][1024],
// VT: bf16 [B][H][64][2048], ctx out: bf16 [B*1024][1024].
// grid (Nq/128, B*H), 8 waves; wave owns 16 q-rows. KVBLK=64, double-buffered
// LDS K/V shared by all 8 waves (XOR-swizzled rows, rule 21). EXACT online
// softmax (defer-max reverted: R7 showed run-to-run divergence with it).
// LDS = 16+16+16 = 48KB; grid 512 -> 2 blocks/CU -> 16 waves/CU (4/SIMD).
__global__ __launch_bounds__(512) void attn_flash(
    const short* __restrict__ Q, const short* __restrict__ Kb,
    const short* __restrict__ VT, short* __restrict__ ctx) {
    __shared__ __align__(16) short kls[2 * 4096];     // 2 x [64 keys][64 d]
    __shared__ __align__(16) short vls[2 * 4096];     // 2 x [64 d][64 keys]
    __shared__ __align__(16) short pls[8 * 1024];     // per-wave 16 rows x 64
    const int tid = threadIdx.x, wave = tid >> 6, lane = tid & 63;
    const int l15 = lane & 15, lhi = lane >> 4;
    const int b = blockIdx.y >> 4, h = blockIdx.y & 15;
    const int q0 = blockIdx.x * 128 + wave * 16;

    const short* qp = Q + ((size_t)(b * 1024 + q0 + l15) * 1024 + h * 64);
    const bf16x8 qf0 = *(const bf16x8*)(qp + lhi * 8);
    const bf16x8 qf1 = *(const bf16x8*)(qp + 32 + lhi * 8);

    f32x4 oa[4];
#pragma unroll
    for (int c = 0; c < 4; ++c) oa[c] = (f32x4){0.f, 0.f, 0.f, 0.f};
    float m[4] = {-1e30f, -1e30f, -1e30f, -1e30f};
    float lsum[4] = {0.f, 0.f, 0.f, 0.f};

    // staging: 1 K chunk + 1 V chunk per thread; wave w covers rows w*8..w*8+7.
    // Source pre-swizzled by ((row&7)<<4), LDS linear (rule 21).
    const int srow = lane >> 3;                           // row&7 within stripe
    const int scol = (((lane & 7) ^ srow) << 4);          // swizzled byte col
    const int krow = wave * 8 + srow;                     // tile row 0..63
    const char* kc = (const char*)(Kb + ((size_t)(b * 2048 + krow) * 1024 + h * 64)) + scol;
    const char* vc = (const char*)(VT + ((size_t)((b * 16 + h) * 64 + krow) * 2048)) + scol;
    const int kdst = wave * 512;                          // shorts (1KB/wave)

    gload16(kc, (char*)&kls[kdst]);
    gload16(vc, (char*)&vls[kdst]);
    kc += 131072; vc += 128;
    __syncthreads();

    short* plw = pls + wave * 1024;
    int cur = 0;

    for (int t = 0; t < 32; ++t) {
        const int nxt = cur ^ 1;
        if (t < 31) {
            gload16(kc, (char*)&kls[nxt * 4096 + kdst]);
            gload16(vc, (char*)&vls[nxt * 4096 + kdst]);
            kc += 131072; vc += 128;
        }
        const char* kcur = (const char*)&kls[cur * 4096];
        const char* vcur = (const char*)&vls[cur * 4096];

        // QK^T: 64 keys x 16 q-rows
        f32x4 s[4];
        __builtin_amdgcn_s_setprio(1);
#pragma unroll
        for (int g = 0; g < 4; ++g) {
            const int key = g * 16 + l15;
            const int sw = (key & 7) << 4;
            const bf16x8 kf0 = *(const bf16x8*)(kcur + key * 128 + ((lhi * 16) ^ sw));
            const bf16x8 kf1 = *(const bf16x8*)(kcur + key * 128 + ((64 + lhi * 16) ^ sw));
            s[g] = mfma16(qf0, kf0, (f32x4){0.f, 0.f, 0.f, 0.f});
            s[g] = mfma16(qf1, kf1, s[g]);
        }
        __builtin_amdgcn_s_setprio(0);

        // exact online softmax: row max over 16 lanes; sums per-lane partials
#pragma unroll
        for (int r = 0; r < 4; ++r) {
            float vm = fmaxf(fmaxf(s[0][r], s[1][r]), fmaxf(s[2][r], s[3][r]));
#pragma unroll
            for (int off = 1; off < 16; off <<= 1)
                vm = fmaxf(vm, __shfl_xor(vm, off, 16));
            const float nm = fmaxf(m[r], vm);
            const float sc = __expf(m[r] - nm);
            m[r] = nm;
            const float p0 = __expf(s[0][r] - nm);
            const float p1 = __expf(s[1][r] - nm);
            const float p2 = __expf(s[2][r] - nm);
            const float p3 = __expf(s[3][r] - nm);
            lsum[r] = lsum[r] * sc + ((p0 + p1) + (p2 + p3));
            unsigned pk01, pk23;
            asm("v_cvt_pk_bf16_f32 %0, %1, %2" : "=v"(pk01) : "v"(p0), "v"(p1));
            asm("v_cvt_pk_bf16_f32 %0, %1, %2" : "=v"(pk23) : "v"(p2), "v"(p3));
            const int prow = lhi * 4 + r;
            char* prb = (char*)plw + prow * 128;
            const int swp = (prow & 7) << 4;
            *(short*)(prb + ((l15 * 2) ^ swp))      = (short)pk01;
            *(short*)(prb + ((32 + l15 * 2) ^ swp)) = (short)(pk01 >> 16);
            *(short*)(prb + ((64 + l15 * 2) ^ swp)) = (short)pk23;
            *(short*)(prb + ((96 + l15 * 2) ^ swp)) = (short)(pk23 >> 16);
            oa[0][r] *= sc; oa[1][r] *= sc; oa[2][r] *= sc; oa[3][r] *= sc;
        }

        // PV
        bf16x8 vb[4][2];
#pragma unroll
        for (int ct = 0; ct < 4; ++ct) {
            const int d = ct * 16 + l15;
            const int sw = (d & 7) << 4;
            vb[ct][0] = *(const bf16x8*)(vcur + d * 128 + ((lhi * 16) ^ sw));
            vb[ct][1] = *(const bf16x8*)(vcur + d * 128 + ((64 + lhi * 16) ^ sw));
        }
        const char* prr = (const char*)plw + l15 * 128;
        const int swr = (l15 & 7) << 4;
        const bf16x8 pa0 = *(const bf16x8*)(prr + ((lhi * 16) ^ swr));
        const bf16x8 pa1 = *(const bf16x8*)(prr + ((64 + lhi * 16) ^ swr));
        __builtin_amdgcn_s_setprio(1);
#pragma unroll
        for (int ct = 0; ct < 4; ++ct) {
            oa[ct] = mfma16(pa0, vb[ct][0], oa[ct]);
            oa[ct] = mfma16(pa1, vb[ct][1], oa[ct]);
        }
        __builtin_amdgcn_s_setprio(0);
        __syncthreads();
        cur = nxt;
    }

    // epilogue: reduce lsum across the 16-lane key groups, normalize, store
#pragma unroll
    for (int i = 0; i < 4; ++i) {
#pragma unroll
        for (int off = 1; off < 16; off <<= 1)
            lsum[i] += __shfl_xor(lsum[i], off, 16);
        lsum[i] = 1.f / lsum[i];
    }
#pragma unroll
    for (int r = 0; r < 4; ++r) {
        const int qrow = q0 + lhi * 4 + r;
        short* cp = ctx + ((size_t)(b * 1024 + qrow) * 1024 + h * 64);
        const float inv = lsum[r];
#pragma unroll
        for (int ct = 0; ct < 4; ++ct)
            cp[ct * 16 + l15] = f2b(oa[ct][r] * inv);
    }
}

// ------------------------------- launcher ----------------------------------

extern "C" void kernel_launch(void* const* d_in, const int* in_sizes, int n_in,
                              void* d_out, int out_size, void* d_ws, size_t ws_size,
                              hipStream_t stream) {
    const float* tgt  = (const float*)d_in[0];
    const float* emb  = (const float*)d_in[1];
    const float* ln_g = (const float*)d_in[2];
    const float* ln_b = (const float*)d_in[3];
    const float* wq = (const float*)d_in[4];  const float* bq = (const float*)d_in[5];
    const float* wk = (const float*)d_in[6];  const float* bk = (const float*)d_in[7];
    const float* wv = (const float*)d_in[8];  const float* bv = (const float*)d_in[9];
    const float* wo = (const float*)d_in[10]; const float* bo = (const float*)d_in[11];
    const float* w1 = (const float*)d_in[12]; const float* b1 = (const float*)d_in[13];
    const float* w2 = (const float*)d_in[14]; const float* b2 = (const float*)d_in[15];

    char* ws = (char*)d_ws;
    const size_t MB = 1024 * 1024;
    short* wqT  = (short*)(ws + 0 * MB);
    short* wkT  = (short*)(ws + 2 * MB);
    short* wvT  = (short*)(ws + 4 * MB);
    short* woT  = (short*)(ws + 6 * MB);
    short* w1T  = (short*)(ws + 8 * MB);    // 8MB
    short* w2T  = (short*)(ws + 16 * MB);   // 8MB
    float* tgt2 = (float*)(ws + 24 * MB);   // 16MB (lifetime disjoint from embB)
    short* embB = (short*)(ws + 40 * MB);   // 16MB (dead after K/V GEMMs)
    short* qn   = (short*)(ws + 56 * MB);   // 8MB (reused as hn)
    short* qbuf = (short*)(ws + 64 * MB);   // 8MB
    short* kbuf = (short*)(ws + 72 * MB);   // 16MB
    short* vbuf = (short*)(ws + 88 * MB);   // 16MB
    short* VT   = (short*)(ws + 104 * MB);  // 16MB
    short* ctx  = (short*)(ws + 120 * MB);  // 8MB
    short* h1   = (short*)(ws + 64 * MB);   // 32MB, reuses q/k/v region (dead by MLP)
    float* outp = (float*)d_out;

    const dim3 tb(32, 8);
    // weights -> bf16 transposed
    transpose_f2b<<<dim3(32, 32), tb, 0, stream>>>(wq, wqT, 1024, 1024);
    transpose_f2b<<<dim3(32, 32), tb, 0, stream>>>(wk, wkT, 1024, 1024);
    transpose_f2b<<<dim3(32, 32), tb, 0, stream>>>(wv, wvT, 1024, 1024);
    transpose_f2b<<<dim3(32, 32), tb, 0, stream>>>(wo, woT, 1024, 1024);
    transpose_f2b<<<dim3(128, 32), tb, 0, stream>>>(w1, w1T, 1024, 4096);
    transpose_f2b<<<dim3(32, 128), tb, 0, stream>>>(w2, w2T, 4096, 1024);
    // emb -> bf16
    conv_f2b<<<8192, 256, 0, stream>>>(emb, embB, 8192 * 1024 / 4);
    // qn = LN(tgt)
    ln_bf16<<<4096, 256, 0, stream>>>(tgt, ln_g, ln_b, qn);
    // q = (qn@wq + bq)/8 ; k/v = emb@w + b
    gemm_bt<1, 0, 0, 0><<<dim3(32, 8), 256, 0, stream>>>(qn, wqT, bq, nullptr, qbuf, 4096, 1024, 1024, 0.125f);
    gemm_bt<1, 0, 0, 0><<<dim3(64, 8), 256, 0, stream>>>(embB, wkT, bk, nullptr, kbuf, 8192, 1024, 1024, 1.f);
    gemm_bt<1, 0, 0, 0><<<dim3(64, 8), 256, 0, stream>>>(embB, wvT, bv, nullptr, vbuf, 8192, 1024, 1024, 1.f);
    transpose_v<<<dim3(64, 2, 64), tb, 0, stream>>>(vbuf, VT);
    // attention (QBLK=128, 8 waves, KVBLK=64, LDS double-buffered, exact SM)
    attn_flash<<<dim3(8, 64), 512, 0, stream>>>(qbuf, kbuf, VT, ctx);
    // tgt2 = tgt + ctx@wo + bo
    gemm_bt<1, 1, 0, 1><<<dim3(32, 8), 256, 0, stream>>>(ctx, woT, bo, tgt, tgt2, 4096, 1024, 1024, 1.f);
    // hn = LN(tgt2)
    ln_bf16<<<4096, 256, 0, stream>>>(tgt2, ln_g, ln_b, qn);
    // h1 = gelu(hn@w1 + b1)
    gemm_bt<1, 0, 1, 0><<<dim3(32, 32), 256, 0, stream>>>(qn, w1T, b1, nullptr, h1, 4096, 4096, 1024, 1.f);
    // out = tgt2 + h1@w2 + b2
    gemm_bt<1, 1, 0, 1><<<dim3(32, 8), 256, 0, stream>>>(h1, w2T, b2, tgt2, outp, 4096, 1024, 4096, 1.f);

    (void)in_sizes; (void)n_in; (void)out_size; (void)ws_size;
}

// Round 10
// 485.051 us; speedup vs baseline: 1.4108x; 1.0393x over previous
//
#include <hip/hip_runtime.h>
#include <cstdint>
#include <cstddef>

// ---------------------------------------------------------------------------
// DecoderBlock (cross-attn + MLP), MI355X gfx950.
// fp32 in/out, bf16 MFMA compute.
// B=4, Nq=1024, Nk=2048, DIM=1024, H=16, HD=64, HID=4096.
// ---------------------------------------------------------------------------

typedef __attribute__((ext_vector_type(8))) short bf16x8;
typedef __attribute__((ext_vector_type(4))) float f32x4;

__device__ __forceinline__ short f2b(float f) {
    unsigned u = __builtin_bit_cast(unsigned, f);
    unsigned r = (u + 0x7FFFu + ((u >> 16) & 1u)) >> 16;   // RNE
    return (short)r;
}

__device__ __forceinline__ f32x4 mfma16(bf16x8 a, bf16x8 b, f32x4 c) {
    return __builtin_amdgcn_mfma_f32_16x16x32_bf16(a, b, c, 0, 0, 0);
}

__device__ __forceinline__ void gload16(const void* g, void* l) {
    __builtin_amdgcn_global_load_lds(
        (const __attribute__((address_space(1))) unsigned int*)g,
        (__attribute__((address_space(3))) unsigned int*)l, 16, 0, 0);
}

// ------------------------------- prep kernels ------------------------------

// fp32 [R][C] -> bf16 [C][R]
__global__ __launch_bounds__(256) void transpose_f2b(
    const float* __restrict__ in, short* __restrict__ out, int R, int C) {
    __shared__ float tile[32][33];
    const int c0 = blockIdx.x * 32, r0 = blockIdx.y * 32;
    const int tx = threadIdx.x, ty = threadIdx.y;   // (32,8)
#pragma unroll
    for (int i = 0; i < 4; ++i)
        tile[ty + 8 * i][tx] = in[(size_t)(r0 + ty + 8 * i) * C + c0 + tx];
    __syncthreads();
#pragma unroll
    for (int i = 0; i < 4; ++i)
        out[(size_t)(c0 + ty + 8 * i) * R + r0 + tx] = f2b(tile[tx][ty + 8 * i]);
}

// fp32 -> bf16 flat (n4 = count/4)
__global__ __launch_bounds__(256) void conv_f2b(
    const float* __restrict__ in, short* __restrict__ out, int n4) {
    int i = blockIdx.x * 256 + threadIdx.x;
    if (i < n4) {
        float4 v = reinterpret_cast<const float4*>(in)[i];
        short4 o;
        o.x = f2b(v.x); o.y = f2b(v.y); o.z = f2b(v.z); o.w = f2b(v.w);
        reinterpret_cast<short4*>(out)[i] = o;
    }
}

// LayerNorm over D=1024, fp32 in -> bf16 out. One row per block (256 thr).
__global__ __launch_bounds__(256) void ln_bf16(
    const float* __restrict__ x, const float* __restrict__ g,
    const float* __restrict__ bb, short* __restrict__ out) {
    const int row = blockIdx.x, tid = threadIdx.x;
    float4 v = reinterpret_cast<const float4*>(x + (size_t)row * 1024)[tid];
    float s = v.x + v.y + v.z + v.w;
    float q = v.x * v.x + v.y * v.y + v.z * v.z + v.w * v.w;
#pragma unroll
    for (int off = 32; off; off >>= 1) {
        s += __shfl_down(s, off);
        q += __shfl_down(q, off);
    }
    __shared__ float ss[4], sq[4];
    const int wave = tid >> 6, lane = tid & 63;
    if (lane == 0) { ss[wave] = s; sq[wave] = q; }
    __syncthreads();
    s = ss[0] + ss[1] + ss[2] + ss[3];
    q = sq[0] + sq[1] + sq[2] + sq[3];
    const float mu = s * (1.f / 1024.f);
    const float var = q * (1.f / 1024.f) - mu * mu;
    const float rs = rsqrtf(var + 1e-5f);
    float4 gg = reinterpret_cast<const float4*>(g)[tid];
    float4 bv = reinterpret_cast<const float4*>(bb)[tid];
    short4 o;
    o.x = f2b((v.x - mu) * rs * gg.x + bv.x);
    o.y = f2b((v.y - mu) * rs * gg.y + bv.y);
    o.z = f2b((v.z - mu) * rs * gg.z + bv.z);
    o.w = f2b((v.w - mu) * rs * gg.w + bv.w);
    reinterpret_cast<short4*>(out + (size_t)row * 1024)[tid] = o;
}

// vbuf bf16 [B][2048][H*64] -> VT bf16 [B][H][64][2048]
__global__ __launch_bounds__(256) void transpose_v(
    const short* __restrict__ vbuf, short* __restrict__ VT) {
    __shared__ short t[32][33];
    const int b = blockIdx.z >> 4, h = blockIdx.z & 15;
    const int n0 = blockIdx.x * 32, d0 = blockIdx.y * 32;
    const int tx = threadIdx.x, ty = threadIdx.y;   // (32,8)
#pragma unroll
    for (int i = 0; i < 4; ++i)
        t[ty + 8 * i][tx] =
            vbuf[(size_t)(b * 2048 + n0 + ty + 8 * i) * 1024 + h * 64 + d0 + tx];
    __syncthreads();
#pragma unroll
    for (int i = 0; i < 4; ++i)
        VT[(size_t)((b * 16 + h) * 64 + d0 + ty + 8 * i) * 2048 + n0 + tx] =
            t[tx][ty + 8 * i];
}

// ------------------------------- GEMM --------------------------------------
// C[M,N] = act( (A[M,K] @ BT[N,K]^T + bias) * scale ) + resid
// A,BT bf16 row-major-along-K. 128x128 tile, 4 waves, BK=64 (2x32 halves).
// Double-buffered LDS with stage-ahead (T3-minimum): tile t+1's loads are
// issued BEFORE computing tile t, so the end-of-iter __syncthreads vmcnt(0)
// drain overlaps with the compute phase instead of exposing full HBM latency.
template <int BIAS, int RESID, int GELU, int OUTF>
__global__ __launch_bounds__(256) void gemm_bt(
    const short* __restrict__ A, const short* __restrict__ BT,
    const float* __restrict__ bias, const float* __restrict__ resid,
    void* __restrict__ out, int M, int N, int K, float scale) {
    __shared__ __align__(16) short As[2][2][128 * 32];   // [buf][half]
    __shared__ __align__(16) short Bs[2][2][128 * 32];
    const int tid = threadIdx.x;
    const int wave = tid >> 6, lane = tid & 63;
    const int l15 = lane & 15, lhi = lane >> 4;
    const int bm = blockIdx.x, bn = blockIdx.y;
    const int wm = (wave >> 1) * 64, wn = (wave & 1) * 64;

    f32x4 acc[4][4];
#pragma unroll
    for (int i = 0; i < 4; ++i)
#pragma unroll
        for (int j = 0; j < 4; ++j) acc[i][j] = (f32x4){0.f, 0.f, 0.f, 0.f};

    const int ob0 = wave * 2048;                 // wave-uniform LDS byte base
    const int o0 = ob0 + lane * 16;
    const int row0 = o0 >> 6, kb0 = o0 & 63;     // 64B per 32-elem row
    const int ob1 = wave * 2048 + 1024;
    const int o1 = ob1 + lane * 16;
    const int row1 = o1 >> 6, kb1 = o1 & 63;

    const char* gA0 = (const char*)A + (size_t)(bm * 128 + row0) * K * 2 + kb0;
    const char* gA1 = (const char*)A + (size_t)(bm * 128 + row1) * K * 2 + kb1;
    const char* gB0 = (const char*)BT + (size_t)(bn * 128 + row0) * K * 2 + kb0;
    const char* gB1 = (const char*)BT + (size_t)(bn * 128 + row1) * K * 2 + kb1;

    auto stage = [&](int buf, int kc0) {
#pragma unroll
        for (int hh = 0; hh < 2; ++hh) {
            const size_t koff = (size_t)(kc0 + hh * 32) * 2;
            gload16(gA0 + koff, (char*)As[buf][hh] + ob0);
            gload16(gA1 + koff, (char*)As[buf][hh] + ob1);
            gload16(gB0 + koff, (char*)Bs[buf][hh] + ob0);
            gload16(gB1 + koff, (char*)Bs[buf][hh] + ob1);
        }
    };

    stage(0, 0);
    __syncthreads();

    int buf = 0;
    for (int k0 = 0; k0 < K; k0 += 64) {
        if (k0 + 64 < K) stage(buf ^ 1, k0 + 64);   // stage-ahead into other buf
#pragma unroll
        for (int hh = 0; hh < 2; ++hh) {
            bf16x8 af[4], bfr[4];
#pragma unroll
            for (int t = 0; t < 4; ++t) {
                af[t]  = *(const bf16x8*)&As[buf][hh][(wm + t * 16 + l15) * 32 + lhi * 8];
                bfr[t] = *(const bf16x8*)&Bs[buf][hh][(wn + t * 16 + l15) * 32 + lhi * 8];
            }
#pragma unroll
            for (int mt = 0; mt < 4; ++mt)
#pragma unroll
                for (int nt = 0; nt < 4; ++nt)
                    acc[mt][nt] = mfma16(af[mt], bfr[nt], acc[mt][nt]);
        }
        __syncthreads();   // drains staged loads; compute phase already covered latency
        buf ^= 1;
    }

#pragma unroll
    for (int mt = 0; mt < 4; ++mt)
#pragma unroll
        for (int nt = 0; nt < 4; ++nt)
#pragma unroll
            for (int r = 0; r < 4; ++r) {
                const int row = bm * 128 + wm + mt * 16 + lhi * 4 + r;
                const int col = bn * 128 + wn + nt * 16 + l15;
                float v = acc[mt][nt][r];
                if (BIAS) v += bias[col];
                v *= scale;
                if (GELU) v = 0.5f * v * (1.f + erff(v * 0.70710678118f));
                if (RESID) v += resid[(size_t)row * N + col];
                if (OUTF)
                    ((float*)out)[(size_t)row * N + col] = v;
                else
                    ((short*)out)[(size_t)row * N + col] = f2b(v);
            }
}

// ---------------------------- flash attention ------------------------------
// Q: bf16 [B*1024][1024] (pre-scaled by 1/8), K: bf16 [B*2048][1024],
// VT: bf16 [B][H][64][2048], ctx out: bf16 [B*1024][1024].
// grid (Nq/128, B*H), 8 waves; wave owns 16 q-rows. KVBLK=64, double-buffered
// LDS K/V shared by all 8 waves (XOR-swizzled rows, rule 21). EXACT online
// softmax (defer-max reverted: R7 showed run-to-run divergence with it).
// LDS = 16+16+16 = 48KB; grid 512 -> 2 blocks/CU -> 16 waves/CU (4/SIMD).
__global__ __launch_bounds__(512) void attn_flash(
    const short* __restrict__ Q, const short* __restrict__ Kb,
    const short* __restrict__ VT, short* __restrict__ ctx) {
    __shared__ __align__(16) short kls[2 * 4096];     // 2 x [64 keys][64 d]
    __shared__ __align__(16) short vls[2 * 4096];     // 2 x [64 d][64 keys]
    __shared__ __align__(16) short pls[8 * 1024];     // per-wave 16 rows x 64
    const int tid = threadIdx.x, wave = tid >> 6, lane = tid & 63;
    const int l15 = lane & 15, lhi = lane >> 4;
    const int b = blockIdx.y >> 4, h = blockIdx.y & 15;
    const int q0 = blockIdx.x * 128 + wave * 16;

    const short* qp = Q + ((size_t)(b * 1024 + q0 + l15) * 1024 + h * 64);
    const bf16x8 qf0 = *(const bf16x8*)(qp + lhi * 8);
    const bf16x8 qf1 = *(const bf16x8*)(qp + 32 + lhi * 8);

    f32x4 oa[4];
#pragma unroll
    for (int c = 0; c < 4; ++c) oa[c] = (f32x4){0.f, 0.f, 0.f, 0.f};
    float m[4] = {-1e30f, -1e30f, -1e30f, -1e30f};
    float lsum[4] = {0.f, 0.f, 0.f, 0.f};

    // staging: 1 K chunk + 1 V chunk per thread; wave w covers rows w*8..w*8+7.
    // Source pre-swizzled by ((row&7)<<4), LDS linear (rule 21).
    const int srow = lane >> 3;                           // row&7 within stripe
    const int scol = (((lane & 7) ^ srow) << 4);          // swizzled byte col
    const int krow = wave * 8 + srow;                     // tile row 0..63
    const char* kc = (const char*)(Kb + ((size_t)(b * 2048 + krow) * 1024 + h * 64)) + scol;
    const char* vc = (const char*)(VT + ((size_t)((b * 16 + h) * 64 + krow) * 2048)) + scol;
    const int kdst = wave * 512;                          // shorts (1KB/wave)

    gload16(kc, (char*)&kls[kdst]);
    gload16(vc, (char*)&vls[kdst]);
    kc += 131072; vc += 128;
    __syncthreads();

    short* plw = pls + wave * 1024;
    int cur = 0;

    for (int t = 0; t < 32; ++t) {
        const int nxt = cur ^ 1;
        if (t < 31) {
            gload16(kc, (char*)&kls[nxt * 4096 + kdst]);
            gload16(vc, (char*)&vls[nxt * 4096 + kdst]);
            kc += 131072; vc += 128;
        }
        const char* kcur = (const char*)&kls[cur * 4096];
        const char* vcur = (const char*)&vls[cur * 4096];

        // QK^T: 64 keys x 16 q-rows
        f32x4 s[4];
        __builtin_amdgcn_s_setprio(1);
#pragma unroll
        for (int g = 0; g < 4; ++g) {
            const int key = g * 16 + l15;
            const int sw = (key & 7) << 4;
            const bf16x8 kf0 = *(const bf16x8*)(kcur + key * 128 + ((lhi * 16) ^ sw));
            const bf16x8 kf1 = *(const bf16x8*)(kcur + key * 128 + ((64 + lhi * 16) ^ sw));
            s[g] = mfma16(qf0, kf0, (f32x4){0.f, 0.f, 0.f, 0.f});
            s[g] = mfma16(qf1, kf1, s[g]);
        }
        __builtin_amdgcn_s_setprio(0);

        // exact online softmax: row max over 16 lanes; sums per-lane partials
#pragma unroll
        for (int r = 0; r < 4; ++r) {
            float vm = fmaxf(fmaxf(s[0][r], s[1][r]), fmaxf(s[2][r], s[3][r]));
#pragma unroll
            for (int off = 1; off < 16; off <<= 1)
                vm = fmaxf(vm, __shfl_xor(vm, off, 16));
            const float nm = fmaxf(m[r], vm);
            const float sc = __expf(m[r] - nm);
            m[r] = nm;
            const float p0 = __expf(s[0][r] - nm);
            const float p1 = __expf(s[1][r] - nm);
            const float p2 = __expf(s[2][r] - nm);
            const float p3 = __expf(s[3][r] - nm);
            lsum[r] = lsum[r] * sc + ((p0 + p1) + (p2 + p3));
            unsigned pk01, pk23;
            asm("v_cvt_pk_bf16_f32 %0, %1, %2" : "=v"(pk01) : "v"(p0), "v"(p1));
            asm("v_cvt_pk_bf16_f32 %0, %1, %2" : "=v"(pk23) : "v"(p2), "v"(p3));
            const int prow = lhi * 4 + r;
            char* prb = (char*)plw + prow * 128;
            const int swp = (prow & 7) << 4;
            *(short*)(prb + ((l15 * 2) ^ swp))      = (short)pk01;
            *(short*)(prb + ((32 + l15 * 2) ^ swp)) = (short)(pk01 >> 16);
            *(short*)(prb + ((64 + l15 * 2) ^ swp)) = (short)pk23;
            *(short*)(prb + ((96 + l15 * 2) ^ swp)) = (short)(pk23 >> 16);
            oa[0][r] *= sc; oa[1][r] *= sc; oa[2][r] *= sc; oa[3][r] *= sc;
        }

        // PV
        bf16x8 vb[4][2];
#pragma unroll
        for (int ct = 0; ct < 4; ++ct) {
            const int d = ct * 16 + l15;
            const int sw = (d & 7) << 4;
            vb[ct][0] = *(const bf16x8*)(vcur + d * 128 + ((lhi * 16) ^ sw));
            vb[ct][1] = *(const bf16x8*)(vcur + d * 128 + ((64 + lhi * 16) ^ sw));
        }
        const char* prr = (const char*)plw + l15 * 128;
        const int swr = (l15 & 7) << 4;
        const bf16x8 pa0 = *(const bf16x8*)(prr + ((lhi * 16) ^ swr));
        const bf16x8 pa1 = *(const bf16x8*)(prr + ((64 + lhi * 16) ^ swr));
        __builtin_amdgcn_s_setprio(1);
#pragma unroll
        for (int ct = 0; ct < 4; ++ct) {
            oa[ct] = mfma16(pa0, vb[ct][0], oa[ct]);
            oa[ct] = mfma16(pa1, vb[ct][1], oa[ct]);
        }
        __builtin_amdgcn_s_setprio(0);
        __syncthreads();
        cur = nxt;
    }

    // epilogue: reduce lsum across the 16-lane key groups, normalize, store
#pragma unroll
    for (int i = 0; i < 4; ++i) {
#pragma unroll
        for (int off = 1; off < 16; off <<= 1)
            lsum[i] += __shfl_xor(lsum[i], off, 16);
        lsum[i] = 1.f / lsum[i];
    }
#pragma unroll
    for (int r = 0; r < 4; ++r) {
        const int qrow = q0 + lhi * 4 + r;
        short* cp = ctx + ((size_t)(b * 1024 + qrow) * 1024 + h * 64);
        const float inv = lsum[r];
#pragma unroll
        for (int ct = 0; ct < 4; ++ct)
            cp[ct * 16 + l15] = f2b(oa[ct][r] * inv);
    }
}

// ------------------------------- launcher ----------------------------------

extern "C" void kernel_launch(void* const* d_in, const int* in_sizes, int n_in,
                              void* d_out, int out_size, void* d_ws, size_t ws_size,
                              hipStream_t stream) {
    const float* tgt  = (const float*)d_in[0];
    const float* emb  = (const float*)d_in[1];
    const float* ln_g = (const float*)d_in[2];
    const float* ln_b = (const float*)d_in[3];
    const float* wq = (const float*)d_in[4];  const float* bq = (const float*)d_in[5];
    const float* wk = (const float*)d_in[6];  const float* bk = (const float*)d_in[7];
    const float* wv = (const float*)d_in[8];  const float* bv = (const float*)d_in[9];
    const float* wo = (const float*)d_in[10]; const float* bo = (const float*)d_in[11];
    const float* w1 = (const float*)d_in[12]; const float* b1 = (const float*)d_in[13];
    const float* w2 = (const float*)d_in[14]; const float* b2 = (const float*)d_in[15];

    char* ws = (char*)d_ws;
    const size_t MB = 1024 * 1024;
    short* wqT  = (short*)(ws + 0 * MB);
    short* wkT  = (short*)(ws + 2 * MB);
    short* wvT  = (short*)(ws + 4 * MB);
    short* woT  = (short*)(ws + 6 * MB);
    short* w1T  = (short*)(ws + 8 * MB);    // 8MB
    short* w2T  = (short*)(ws + 16 * MB);   // 8MB
    float* tgt2 = (float*)(ws + 24 * MB);   // 16MB (lifetime disjoint from embB)
    short* embB = (short*)(ws + 40 * MB);   // 16MB (dead after K/V GEMMs)
    short* qn   = (short*)(ws + 56 * MB);   // 8MB (reused as hn)
    short* qbuf = (short*)(ws + 64 * MB);   // 8MB
    short* kbuf = (short*)(ws + 72 * MB);   // 16MB
    short* vbuf = (short*)(ws + 88 * MB);   // 16MB
    short* VT   = (short*)(ws + 104 * MB);  // 16MB
    short* ctx  = (short*)(ws + 120 * MB);  // 8MB
    short* h1   = (short*)(ws + 64 * MB);   // 32MB, reuses q/k/v region (dead by MLP)
    float* outp = (float*)d_out;

    const dim3 tb(32, 8);
    // weights -> bf16 transposed
    transpose_f2b<<<dim3(32, 32), tb, 0, stream>>>(wq, wqT, 1024, 1024);
    transpose_f2b<<<dim3(32, 32), tb, 0, stream>>>(wk, wkT, 1024, 1024);
    transpose_f2b<<<dim3(32, 32), tb, 0, stream>>>(wv, wvT, 1024, 1024);
    transpose_f2b<<<dim3(32, 32), tb, 0, stream>>>(wo, woT, 1024, 1024);
    transpose_f2b<<<dim3(128, 32), tb, 0, stream>>>(w1, w1T, 1024, 4096);
    transpose_f2b<<<dim3(32, 128), tb, 0, stream>>>(w2, w2T, 4096, 1024);
    // emb -> bf16
    conv_f2b<<<8192, 256, 0, stream>>>(emb, embB, 8192 * 1024 / 4);
    // qn = LN(tgt)
    ln_bf16<<<4096, 256, 0, stream>>>(tgt, ln_g, ln_b, qn);
    // q = (qn@wq + bq)/8 ; k/v = emb@w + b
    gemm_bt<1, 0, 0, 0><<<dim3(32, 8), 256, 0, stream>>>(qn, wqT, bq, nullptr, qbuf, 4096, 1024, 1024, 0.125f);
    gemm_bt<1, 0, 0, 0><<<dim3(64, 8), 256, 0, stream>>>(embB, wkT, bk, nullptr, kbuf, 8192, 1024, 1024, 1.f);
    gemm_bt<1, 0, 0, 0><<<dim3(64, 8), 256, 0, stream>>>(embB, wvT, bv, nullptr, vbuf, 8192, 1024, 1024, 1.f);
    transpose_v<<<dim3(64, 2, 64), tb, 0, stream>>>(vbuf, VT);
    // attention (QBLK=128, 8 waves, KVBLK=64, LDS double-buffered, exact SM)
    attn_flash<<<dim3(8, 64), 512, 0, stream>>>(qbuf, kbuf, VT, ctx);
    // tgt2 = tgt + ctx@wo + bo
    gemm_bt<1, 1, 0, 1><<<dim3(32, 8), 256, 0, stream>>>(ctx, woT, bo, tgt, tgt2, 4096, 1024, 1024, 1.f);
    // hn = LN(tgt2)
    ln_bf16<<<4096, 256, 0, stream>>>(tgt2, ln_g, ln_b, qn);
    // h1 = gelu(hn@w1 + b1)
    gemm_bt<1, 0, 1, 0><<<dim3(32, 32), 256, 0, stream>>>(qn, w1T, b1, nullptr, h1, 4096, 4096, 1024, 1.f);
    // out = tgt2 + h1@w2 + b2
    gemm_bt<1, 1, 0, 1><<<dim3(32, 8), 256, 0, stream>>>(h1, w2T, b2, tgt2, outp, 4096, 1024, 4096, 1.f);

    (void)in_sizes; (void)n_in; (void)out_size; (void)ws_size;
}